// Round 1
// baseline (3083.575 us; speedup 1.0000x reference)
//
#include <hip/hip_runtime.h>
#include <hip/hip_bf16.h>

#define N_NODES_C 100000
#define N_EDGES_C 800000
#define DIM_C 300
#define NGRAPH_C 64

// ---------------- degree count ----------------
__global__ __launch_bounds__(256) void k_count(const int* __restrict__ dst,
                                               unsigned* __restrict__ counts, int e) {
    int i = blockIdx.x * 256 + threadIdx.x;
    if (i < e) atomicAdd(&counts[dst[i]], 1u);
}

__global__ __launch_bounds__(256) void k_dinv(const unsigned* __restrict__ counts,
                                              float* __restrict__ dinv, int n) {
    int i = blockIdx.x * 256 + threadIdx.x;
    if (i < n) dinv[i] = rsqrtf((float)(counts[i] + 1u));  // +1 self loop
}

// ---------------- 2-level exclusive scan over counts ----------------
__global__ __launch_bounds__(256) void k_blocksum(const unsigned* __restrict__ counts,
                                                  unsigned* __restrict__ partials, int n) {
    __shared__ unsigned s[256];
    int base = blockIdx.x * 1024;
    unsigned sum = 0;
    for (int j = threadIdx.x; j < 1024; j += 256) {
        int i = base + j;
        sum += (i < n) ? counts[i] : 0u;
    }
    s[threadIdx.x] = sum;
    __syncthreads();
    for (int off = 128; off > 0; off >>= 1) {
        if (threadIdx.x < (unsigned)off) s[threadIdx.x] += s[threadIdx.x + off];
        __syncthreads();
    }
    if (threadIdx.x == 0) partials[blockIdx.x] = s[0];
}

__global__ __launch_bounds__(128) void k_scanpartials(unsigned* __restrict__ partials, int nb) {
    __shared__ unsigned s[128];
    int t = threadIdx.x;
    s[t] = (t < nb) ? partials[t] : 0u;
    __syncthreads();
    if (t == 0) {
        unsigned run = 0;
        for (int i = 0; i < nb; ++i) { unsigned v = s[i]; s[i] = run; run += v; }
    }
    __syncthreads();
    if (t < nb) partials[t] = s[t];
}

__global__ __launch_bounds__(256) void k_scanblock(const unsigned* __restrict__ counts,
                                                   const unsigned* __restrict__ partials,
                                                   unsigned* __restrict__ row_start, int n) {
    __shared__ unsigned s[256];
    int base = blockIdx.x * 1024;
    int t = threadIdx.x;
    unsigned v[4];
    unsigned tsum = 0;
#pragma unroll
    for (int j = 0; j < 4; ++j) {
        int i = base + t * 4 + j;
        v[j] = (i < n) ? counts[i] : 0u;
        tsum += v[j];
    }
    s[t] = tsum;
    __syncthreads();
    for (int off = 1; off < 256; off <<= 1) {
        unsigned x = (t >= off) ? s[t - off] : 0u;
        __syncthreads();
        s[t] += x;
        __syncthreads();
    }
    unsigned excl = (t > 0 ? s[t - 1] : 0u) + partials[blockIdx.x];
#pragma unroll
    for (int j = 0; j < 4; ++j) {
        int i = base + t * 4 + j;
        if (i < n) {
            row_start[i] = excl;
            excl += v[j];
            if (i == n - 1) row_start[n] = excl;
        }
    }
}

// ---------------- CSR fill ----------------
__global__ __launch_bounds__(256) void k_fill(const int* __restrict__ src, const int* __restrict__ dst,
                                              const unsigned* __restrict__ row_start,
                                              unsigned* __restrict__ fill,
                                              unsigned* __restrict__ col, float* __restrict__ val,
                                              const float* __restrict__ dinv, int e) {
    int i = blockIdx.x * 256 + threadIdx.x;
    if (i >= e) return;
    int d = dst[i], s0 = src[i];
    unsigned pos = row_start[d] + atomicAdd(&fill[d], 1u);
    col[pos] = (unsigned)s0;
    val[pos] = dinv[s0] * dinv[d];
}

// ---------------- embedding ----------------
__global__ __launch_bounds__(256) void k_embed(const int* __restrict__ x,
                                               const float4* __restrict__ at4,
                                               const float4* __restrict__ wt4,
                                               float4* __restrict__ h4, int n75) {
    int idx = blockIdx.x * 256 + threadIdx.x;
    if (idx >= n75) return;
    int i = idx / 75;
    int c = idx - i * 75;
    int a = x[2 * i], w = x[2 * i + 1];
    float4 av = at4[a * 75 + c];
    float4 wv = wt4[w * 75 + c];
    float4 o;
    o.x = av.x + wv.x; o.y = av.y + wv.y; o.z = av.z + wv.z; o.w = av.w + wv.w;
    h4[idx] = o;
}

// ---------------- GEMM: C[M,300] = A[M,300] * W[300,300], fp32 ----------------
#define BM 64
#define BN 64
#define BK 60

__global__ __launch_bounds__(256) void k_gemm(const float* __restrict__ A,
                                              const float* __restrict__ W,
                                              float* __restrict__ C, int M) {
    __shared__ float As[BK][BM];  // transposed: As[k][m]
    __shared__ float Bs[BK][BN];
    int bm0 = blockIdx.x * BM;
    int bn0 = blockIdx.y * BN;
    int tid = threadIdx.x;
    int tm = tid >> 4;   // 0..15
    int tn = tid & 15;   // 0..15
    float acc[4][4] = {};
    for (int k0 = 0; k0 < 300; k0 += BK) {
        // stage A: BM x BK = 3840 elements, 15 per thread
#pragma unroll
        for (int r = 0; r < 15; ++r) {
            int idx = r * 256 + tid;
            int m = idx / BK;
            int k = idx - m * BK;
            int row = bm0 + m;
            float v = (row < M) ? A[(long)row * 300 + k0 + k] : 0.f;
            As[k][m] = v;
        }
        // stage B: BK x BN = 3840 elements
#pragma unroll
        for (int r = 0; r < 15; ++r) {
            int idx = r * 256 + tid;
            int k = idx >> 6;
            int nn = idx & 63;
            int colg = bn0 + nn;
            float v = (colg < 300) ? W[(k0 + k) * 300 + colg] : 0.f;
            Bs[k][nn] = v;
        }
        __syncthreads();
#pragma unroll 4
        for (int k = 0; k < BK; ++k) {
            float4 a4 = *(const float4*)&As[k][tm * 4];
            float4 b4 = *(const float4*)&Bs[k][tn * 4];
            float a[4] = {a4.x, a4.y, a4.z, a4.w};
            float b[4] = {b4.x, b4.y, b4.z, b4.w};
#pragma unroll
            for (int i = 0; i < 4; ++i)
#pragma unroll
                for (int j = 0; j < 4; ++j) acc[i][j] += a[i] * b[j];
        }
        __syncthreads();
    }
#pragma unroll
    for (int i = 0; i < 4; ++i) {
        int row = bm0 + tm * 4 + i;
        if (row < M) {
#pragma unroll
            for (int j = 0; j < 4; ++j) {
                int colg = bn0 + tn * 4 + j;
                if (colg < 300) C[(long)row * 300 + colg] = acc[i][j];
            }
        }
    }
}

// ---------------- aggregation: h = b + D^-1/2 A D^-1/2 hw ----------------
__global__ __launch_bounds__(256) void k_agg(const float4* __restrict__ hw,
                                             const float* __restrict__ dinv,
                                             const unsigned* __restrict__ row_start,
                                             const unsigned* __restrict__ col,
                                             const float* __restrict__ val,
                                             const float4* __restrict__ b4,
                                             float4* __restrict__ hout, int n) {
    int idx = blockIdx.x * 256 + threadIdx.x;
    if (idx >= n * 75) return;
    int i = idx / 75;
    int c = idx - i * 75;
    float d = dinv[i];
    float4 acc = b4[c];
    float4 hv = hw[(long)i * 75 + c];
    float sn = d * d;
    acc.x += sn * hv.x; acc.y += sn * hv.y; acc.z += sn * hv.z; acc.w += sn * hv.w;
    unsigned e0 = row_start[i], e1 = row_start[i + 1];
    for (unsigned e = e0; e < e1; ++e) {
        float w = val[e];
        float4 m = hw[(long)col[e] * 75 + c];
        acc.x += w * m.x; acc.y += w * m.y; acc.z += w * m.z; acc.w += w * m.w;
    }
    hout[(long)i * 75 + c] = acc;
}

// ---------------- graph boundaries (batch sorted) ----------------
__global__ __launch_bounds__(128) void k_gstart(const int* __restrict__ batch,
                                                int* __restrict__ gstart, int n, int ngraph) {
    int g = threadIdx.x;
    if (g > ngraph) return;
    if (g == ngraph) { gstart[g] = n; return; }
    int lo = 0, hi = n;
    while (lo < hi) {
        int mid = (lo + hi) >> 1;
        if (batch[mid] < g) lo = mid + 1; else hi = mid;
    }
    gstart[g] = lo;
}

// ---------------- pool: per-graph sums (64 graphs x 8 chunks) ----------------
__global__ __launch_bounds__(256) void k_pool(const float* __restrict__ h,
                                              const int* __restrict__ gstart,
                                              float* __restrict__ psum) {
    int g = blockIdx.x >> 3;
    int chunk = blockIdx.x & 7;
    int lo = gstart[g], hi = gstart[g + 1];
    int cnt = hi - lo;
    int s = lo + (int)((long)cnt * chunk / 8);
    int e2 = lo + (int)((long)cnt * (chunk + 1) / 8);
    for (int c = threadIdx.x; c < 300; c += 256) {
        float acc = 0.f;
        for (int i = s; i < e2; ++i) acc += h[(long)i * 300 + c];
        atomicAdd(&psum[g * 300 + c], acc);
    }
}

__global__ __launch_bounds__(256) void k_div(const float* __restrict__ psum,
                                             const int* __restrict__ gstart,
                                             float* __restrict__ out) {
    int j = blockIdx.x * 256 + threadIdx.x;
    if (j >= NGRAPH_C * 300) return;
    int g = j / 300;
    int c2 = gstart[g + 1] - gstart[g];
    out[j] = psum[j] / (float)(c2 > 0 ? c2 : 1);
}

// ---------------- launch ----------------
extern "C" void kernel_launch(void* const* d_in, const int* in_sizes, int n_in,
                              void* d_out, int out_size, void* d_ws, size_t ws_size,
                              hipStream_t stream) {
    const int*   x     = (const int*)d_in[0];
    const int*   ei    = (const int*)d_in[1];
    const int*   batch = (const int*)d_in[2];
    const float* at    = (const float*)d_in[3];
    const float* wt    = (const float*)d_in[4];
    const float* W     = (const float*)d_in[5];
    const float* b     = (const float*)d_in[6];

    const int n = in_sizes[0] / 2;   // 100000
    const int e = in_sizes[1] / 2;   // 800000
    const int n75 = n * 75;

    // workspace carve (256B aligned)
    char* ws = (char*)d_ws;
    size_t off = 0;
    auto carve = [&](size_t bytes) {
        void* p = ws + off;
        off += (bytes + 255) & ~(size_t)255;
        return p;
    };
    float*    h         = (float*)carve((size_t)n * 300 * 4);
    float*    hw        = (float*)carve((size_t)n * 300 * 4);
    float*    dinv      = (float*)carve((size_t)n * 4);
    unsigned* counts    = (unsigned*)carve((size_t)n * 4);
    unsigned* fill      = (unsigned*)carve((size_t)n * 4);
    unsigned* row_start = (unsigned*)carve((size_t)(n + 1) * 4);
    unsigned* partials  = (unsigned*)carve(1024 * 4);
    unsigned* colb      = (unsigned*)carve((size_t)e * 4);
    float*    val       = (float*)carve((size_t)e * 4);
    int*      gstart    = (int*)carve(65 * 4);
    float*    psum      = (float*)carve((size_t)NGRAPH_C * 300 * 4);

    const int* src = ei;
    const int* dst = ei + e;

    hipMemsetAsync(counts, 0, (size_t)n * 4, stream);
    hipMemsetAsync(fill, 0, (size_t)n * 4, stream);
    hipMemsetAsync(psum, 0, (size_t)NGRAPH_C * 300 * 4, stream);

    int eb = (e + 255) / 256;
    int nb256 = (n + 255) / 256;
    int NB = (n + 1023) / 1024;  // 98

    k_count<<<eb, 256, 0, stream>>>(dst, counts, e);
    k_dinv<<<nb256, 256, 0, stream>>>(counts, dinv, n);
    k_blocksum<<<NB, 256, 0, stream>>>(counts, partials, n);
    k_scanpartials<<<1, 128, 0, stream>>>(partials, NB);
    k_scanblock<<<NB, 256, 0, stream>>>(counts, partials, row_start, n);
    k_fill<<<eb, 256, 0, stream>>>(src, dst, row_start, fill, colb, val, dinv, e);
    k_gstart<<<1, 128, 0, stream>>>(batch, gstart, n, NGRAPH_C);

    int gb = (n75 + 255) / 256;
    k_embed<<<gb, 256, 0, stream>>>(x, (const float4*)at, (const float4*)wt, (float4*)h, n75);

    dim3 ggrid((n + BM - 1) / BM, (300 + BN - 1) / BN);
    for (int hop = 0; hop < 3; ++hop) {
        k_gemm<<<ggrid, 256, 0, stream>>>(h, W, hw, n);
        k_agg<<<gb, 256, 0, stream>>>((const float4*)hw, dinv, row_start, colb, val,
                                      (const float4*)b, (float4*)h, n);
    }

    k_pool<<<NGRAPH_C * 8, 256, 0, stream>>>(h, gstart, psum);
    k_div<<<(NGRAPH_C * 300 + 255) / 256, 256, 0, stream>>>(psum, gstart, (float*)d_out);
}

// Round 2
// 1212.144 us; speedup vs baseline: 2.5439x; 2.5439x over previous
//
#include <hip/hip_runtime.h>
#include <hip/hip_bf16.h>

#define N_NODES_C 100000
#define N_EDGES_C 800000
#define DIM_C 300
#define NGRAPH_C 64

typedef short bf16x8 __attribute__((ext_vector_type(8)));
typedef float f32x4 __attribute__((ext_vector_type(4)));

// ---- bf16 helpers (manual RN-even, no API drift) ----
__device__ __forceinline__ unsigned f_as_u(float f) { union { float f; unsigned u; } c; c.f = f; return c.u; }
__device__ __forceinline__ float u_as_f(unsigned u) { union { unsigned u; float f; } c; c.u = u; return c.f; }
__device__ __forceinline__ short f2bf_rn(float f) {
    unsigned u = f_as_u(f);
    unsigned r = (u + 0x7FFFu + ((u >> 16) & 1u)) >> 16;
    return (short)r;
}
__device__ __forceinline__ float bf2f(short s) { return u_as_f(((unsigned)(unsigned short)s) << 16); }

// ---------------- degree count ----------------
__global__ __launch_bounds__(256) void k_count(const int* __restrict__ dst,
                                               unsigned* __restrict__ counts, int e) {
    int i = blockIdx.x * 256 + threadIdx.x;
    if (i < e) atomicAdd(&counts[dst[i]], 1u);
}

__global__ __launch_bounds__(256) void k_dinv(const unsigned* __restrict__ counts,
                                              float* __restrict__ dinv, int n) {
    int i = blockIdx.x * 256 + threadIdx.x;
    if (i < n) dinv[i] = rsqrtf((float)(counts[i] + 1u));  // +1 self loop
}

// ---------------- 2-level exclusive scan over counts ----------------
__global__ __launch_bounds__(256) void k_blocksum(const unsigned* __restrict__ counts,
                                                  unsigned* __restrict__ partials, int n) {
    __shared__ unsigned s[256];
    int base = blockIdx.x * 1024;
    unsigned sum = 0;
    for (int j = threadIdx.x; j < 1024; j += 256) {
        int i = base + j;
        sum += (i < n) ? counts[i] : 0u;
    }
    s[threadIdx.x] = sum;
    __syncthreads();
    for (int off = 128; off > 0; off >>= 1) {
        if (threadIdx.x < (unsigned)off) s[threadIdx.x] += s[threadIdx.x + off];
        __syncthreads();
    }
    if (threadIdx.x == 0) partials[blockIdx.x] = s[0];
}

__global__ __launch_bounds__(128) void k_scanpartials(unsigned* __restrict__ partials, int nb) {
    __shared__ unsigned s[128];
    int t = threadIdx.x;
    s[t] = (t < nb) ? partials[t] : 0u;
    __syncthreads();
    if (t == 0) {
        unsigned run = 0;
        for (int i = 0; i < nb; ++i) { unsigned v = s[i]; s[i] = run; run += v; }
    }
    __syncthreads();
    if (t < nb) partials[t] = s[t];
}

__global__ __launch_bounds__(256) void k_scanblock(const unsigned* __restrict__ counts,
                                                   const unsigned* __restrict__ partials,
                                                   unsigned* __restrict__ row_start, int n) {
    __shared__ unsigned s[256];
    int base = blockIdx.x * 1024;
    int t = threadIdx.x;
    unsigned v[4];
    unsigned tsum = 0;
#pragma unroll
    for (int j = 0; j < 4; ++j) {
        int i = base + t * 4 + j;
        v[j] = (i < n) ? counts[i] : 0u;
        tsum += v[j];
    }
    s[t] = tsum;
    __syncthreads();
    for (int off = 1; off < 256; off <<= 1) {
        unsigned x = (t >= off) ? s[t - off] : 0u;
        __syncthreads();
        s[t] += x;
        __syncthreads();
    }
    unsigned excl = (t > 0 ? s[t - 1] : 0u) + partials[blockIdx.x];
#pragma unroll
    for (int j = 0; j < 4; ++j) {
        int i = base + t * 4 + j;
        if (i < n) {
            row_start[i] = excl;
            excl += v[j];
            if (i == n - 1) row_start[n] = excl;
        }
    }
}

// ---------------- CSR fill ----------------
__global__ __launch_bounds__(256) void k_fill(const int* __restrict__ src, const int* __restrict__ dst,
                                              const unsigned* __restrict__ row_start,
                                              unsigned* __restrict__ fill,
                                              unsigned* __restrict__ col, float* __restrict__ val,
                                              const float* __restrict__ dinv, int e) {
    int i = blockIdx.x * 256 + threadIdx.x;
    if (i >= e) return;
    int d = dst[i], s0 = src[i];
    unsigned pos = row_start[d] + atomicAdd(&fill[d], 1u);
    col[pos] = (unsigned)s0;
    val[pos] = dinv[s0] * dinv[d];
}

// ---------------- embedding ----------------
__global__ __launch_bounds__(256) void k_embed(const int* __restrict__ x,
                                               const float4* __restrict__ at4,
                                               const float4* __restrict__ wt4,
                                               float4* __restrict__ h4, int n75) {
    int idx = blockIdx.x * 256 + threadIdx.x;
    if (idx >= n75) return;
    int i = idx / 75;
    int c = idx - i * 75;
    int a = x[2 * i], w = x[2 * i + 1];
    float4 av = at4[a * 75 + c];
    float4 wv = wt4[w * 75 + c];
    float4 o;
    o.x = av.x + wv.x; o.y = av.y + wv.y; o.z = av.z + wv.z; o.w = av.w + wv.w;
    h4[idx] = o;
}

// ---------------- W pack: fragment-layout bf16 hi/lo, padded 320x320 ----------------
// Wp[(kt*20+nt)*64 + lane] is a bf16x8: element j = W[kt*32 + (lane>>4)*8 + j][nt*16 + (lane&15)]
__global__ __launch_bounds__(256) void k_packW(const float* __restrict__ W,
                                               short* __restrict__ WpHi, short* __restrict__ WpLo) {
    int t = blockIdx.x * 256 + threadIdx.x;
    if (t >= 10 * 20 * 64) return;
    int lane = t & 63;
    int frag = t >> 6;           // kt*20 + nt
    int kt = frag / 20;
    int nt = frag - kt * 20;
    int kbase = kt * 32 + (lane >> 4) * 8;
    int ncol = nt * 16 + (lane & 15);
    short hi[8], lo[8];
#pragma unroll
    for (int j = 0; j < 8; ++j) {
        int k = kbase + j;
        float v = (k < 300 && ncol < 300) ? W[k * 300 + ncol] : 0.f;
        short h = f2bf_rn(v);
        float r = v - bf2f(h);
        hi[j] = h;
        lo[j] = f2bf_rn(r);
    }
    bf16x8 vh, vl;
#pragma unroll
    for (int j = 0; j < 8; ++j) { vh[j] = hi[j]; vl[j] = lo[j]; }
    *(bf16x8*)&WpHi[(size_t)t * 8] = vh;
    *(bf16x8*)&WpLo[(size_t)t * 8] = vl;
}

// ---------------- GEMM: C[M,300] = A[M,300] * W, bf16 MFMA 3-pass hi/lo ----------------
// Block: 256 thr (4 waves). Block tile BM=128 x BN=160. Wave: 32 rows (2 m-frags) x 160 cols (10 n-frags).
// K padded to 320 (10 steps of 32). A staged fp32->LDS bf16 hi/lo per k-step.
#define G_BM 128
#define G_BN 160
#define LDS_RS 40  // row stride in bf16 (32 + 8 pad -> 2-way max bank aliasing, free)

__global__ __launch_bounds__(256) void k_gemm_mfma(const float* __restrict__ A,
                                                   const short* __restrict__ WpHi,
                                                   const short* __restrict__ WpLo,
                                                   float* __restrict__ C, int M) {
    __shared__ short AsHi[G_BM * LDS_RS];
    __shared__ short AsLo[G_BM * LDS_RS];
    const int tid = threadIdx.x;
    const int wave = tid >> 6;
    const int lane = tid & 63;
    const int r = lane & 15;
    const int quad = lane >> 4;
    const int bm0 = blockIdx.x * G_BM;
    const int bn = blockIdx.y;             // 0..1
    const int srow = tid >> 1;             // staging row 0..127
    const int skk = (tid & 1) * 16;        // staging k offset 0 or 16

    f32x4 acc[2][10];
#pragma unroll
    for (int mi = 0; mi < 2; ++mi)
#pragma unroll
        for (int nt = 0; nt < 10; ++nt) acc[mi][nt] = (f32x4){0.f, 0.f, 0.f, 0.f};

    for (int kt = 0; kt < 10; ++kt) {
        const int k0 = kt * 32;
        // ---- stage A[bm0..+128][k0..+32] as bf16 hi/lo into LDS ----
        {
            int grow = bm0 + srow;
            float v[16];
            if (grow < M && k0 + skk + 15 < 300) {
                const float4* p = (const float4*)&A[(size_t)grow * 300 + k0 + skk];
#pragma unroll
                for (int q = 0; q < 4; ++q) {
                    float4 f = p[q];
                    v[q * 4 + 0] = f.x; v[q * 4 + 1] = f.y; v[q * 4 + 2] = f.z; v[q * 4 + 3] = f.w;
                }
            } else {
#pragma unroll
                for (int j = 0; j < 16; ++j) {
                    int k = k0 + skk + j;
                    v[j] = (grow < M && k < 300) ? A[(size_t)grow * 300 + k] : 0.f;
                }
            }
            short hi[16], lo[16];
#pragma unroll
            for (int j = 0; j < 16; ++j) {
                short h = f2bf_rn(v[j]);
                hi[j] = h;
                lo[j] = f2bf_rn(v[j] - bf2f(h));
            }
            bf16x8 h0, h1, l0, l1;
#pragma unroll
            for (int j = 0; j < 8; ++j) { h0[j] = hi[j]; h1[j] = hi[8 + j]; l0[j] = lo[j]; l1[j] = lo[8 + j]; }
            int base = srow * LDS_RS + skk;
            *(bf16x8*)&AsHi[base] = h0;
            *(bf16x8*)&AsHi[base + 8] = h1;
            *(bf16x8*)&AsLo[base] = l0;
            *(bf16x8*)&AsLo[base + 8] = l1;
        }
        __syncthreads();

        // ---- A fragments ----
        bf16x8 ah[2], al[2];
#pragma unroll
        for (int mi = 0; mi < 2; ++mi) {
            int lrow = wave * 32 + mi * 16 + r;
            int addr = lrow * LDS_RS + quad * 8;
            ah[mi] = *(const bf16x8*)&AsHi[addr];
            al[mi] = *(const bf16x8*)&AsLo[addr];
        }

        // ---- B fragments from packed W (L2-resident) + MFMA ----
#pragma unroll
        for (int nt = 0; nt < 10; ++nt) {
            int ntg = bn * 10 + nt;
            size_t fidx = ((size_t)(kt * 20 + ntg) * 64 + lane) * 8;
            bf16x8 bh = *(const bf16x8*)&WpHi[fidx];
            bf16x8 bl = *(const bf16x8*)&WpLo[fidx];
#pragma unroll
            for (int mi = 0; mi < 2; ++mi) {
                acc[mi][nt] = __builtin_amdgcn_mfma_f32_16x16x32_bf16(ah[mi], bh, acc[mi][nt], 0, 0, 0);
                acc[mi][nt] = __builtin_amdgcn_mfma_f32_16x16x32_bf16(ah[mi], bl, acc[mi][nt], 0, 0, 0);
                acc[mi][nt] = __builtin_amdgcn_mfma_f32_16x16x32_bf16(al[mi], bh, acc[mi][nt], 0, 0, 0);
            }
        }
        __syncthreads();
    }

    // ---- epilogue: C/D layout col=lane&15, row=quad*4+reg ----
#pragma unroll
    for (int mi = 0; mi < 2; ++mi) {
#pragma unroll
        for (int nt = 0; nt < 10; ++nt) {
            int col = bn * G_BN + nt * 16 + r;
            if (col >= 300) continue;
            int row0 = bm0 + wave * 32 + mi * 16 + quad * 4;
            f32x4 c = acc[mi][nt];
#pragma unroll
            for (int reg = 0; reg < 4; ++reg) {
                int row = row0 + reg;
                if (row < M) C[(size_t)row * 300 + col] = c[reg];
            }
        }
    }
}

// ---------------- aggregation: h = b + D^-1/2 A D^-1/2 hw ----------------
__global__ __launch_bounds__(256) void k_agg(const float4* __restrict__ hw,
                                             const float* __restrict__ dinv,
                                             const unsigned* __restrict__ row_start,
                                             const unsigned* __restrict__ col,
                                             const float* __restrict__ val,
                                             const float4* __restrict__ b4,
                                             float4* __restrict__ hout, int n) {
    int idx = blockIdx.x * 256 + threadIdx.x;
    if (idx >= n * 75) return;
    int i = idx / 75;
    int c = idx - i * 75;
    float d = dinv[i];
    float4 acc = b4[c];
    float4 hv = hw[(size_t)i * 75 + c];
    float sn = d * d;
    acc.x += sn * hv.x; acc.y += sn * hv.y; acc.z += sn * hv.z; acc.w += sn * hv.w;
    unsigned e0 = row_start[i], e1 = row_start[i + 1];
    for (unsigned e = e0; e < e1; ++e) {
        float w = val[e];
        float4 m = hw[(size_t)col[e] * 75 + c];
        acc.x += w * m.x; acc.y += w * m.y; acc.z += w * m.z; acc.w += w * m.w;
    }
    hout[(size_t)i * 75 + c] = acc;
}

// ---------------- graph boundaries (batch sorted) ----------------
__global__ __launch_bounds__(128) void k_gstart(const int* __restrict__ batch,
                                                int* __restrict__ gstart, int n, int ngraph) {
    int g = threadIdx.x;
    if (g > ngraph) return;
    if (g == ngraph) { gstart[g] = n; return; }
    int lo = 0, hi = n;
    while (lo < hi) {
        int mid = (lo + hi) >> 1;
        if (batch[mid] < g) lo = mid + 1; else hi = mid;
    }
    gstart[g] = lo;
}

// ---------------- pool: per-graph sums (64 graphs x 8 chunks) ----------------
__global__ __launch_bounds__(256) void k_pool(const float* __restrict__ h,
                                              const int* __restrict__ gstart,
                                              float* __restrict__ psum) {
    int g = blockIdx.x >> 3;
    int chunk = blockIdx.x & 7;
    int lo = gstart[g], hi = gstart[g + 1];
    int cnt = hi - lo;
    int s = lo + (int)((long)cnt * chunk / 8);
    int e2 = lo + (int)((long)cnt * (chunk + 1) / 8);
    for (int c = threadIdx.x; c < 300; c += 256) {
        float acc = 0.f;
        for (int i = s; i < e2; ++i) acc += h[(size_t)i * 300 + c];
        atomicAdd(&psum[g * 300 + c], acc);
    }
}

__global__ __launch_bounds__(256) void k_div(const float* __restrict__ psum,
                                             const int* __restrict__ gstart,
                                             float* __restrict__ out) {
    int j = blockIdx.x * 256 + threadIdx.x;
    if (j >= NGRAPH_C * 300) return;
    int g = j / 300;
    int c2 = gstart[g + 1] - gstart[g];
    out[j] = psum[j] / (float)(c2 > 0 ? c2 : 1);
}

// ---------------- launch ----------------
extern "C" void kernel_launch(void* const* d_in, const int* in_sizes, int n_in,
                              void* d_out, int out_size, void* d_ws, size_t ws_size,
                              hipStream_t stream) {
    const int*   x     = (const int*)d_in[0];
    const int*   ei    = (const int*)d_in[1];
    const int*   batch = (const int*)d_in[2];
    const float* at    = (const float*)d_in[3];
    const float* wt    = (const float*)d_in[4];
    const float* W     = (const float*)d_in[5];
    const float* b     = (const float*)d_in[6];

    const int n = in_sizes[0] / 2;   // 100000
    const int e = in_sizes[1] / 2;   // 800000
    const int n75 = n * 75;

    // workspace carve (256B aligned)
    char* ws = (char*)d_ws;
    size_t off = 0;
    auto carve = [&](size_t bytes) {
        void* p = ws + off;
        off += (bytes + 255) & ~(size_t)255;
        return p;
    };
    float*    h         = (float*)carve((size_t)n * 300 * 4);
    float*    hw        = (float*)carve((size_t)n * 300 * 4);
    float*    dinv      = (float*)carve((size_t)n * 4);
    unsigned* counts    = (unsigned*)carve((size_t)n * 4);
    unsigned* fill      = (unsigned*)carve((size_t)n * 4);
    unsigned* row_start = (unsigned*)carve((size_t)(n + 1) * 4);
    unsigned* partials  = (unsigned*)carve(1024 * 4);
    unsigned* colb      = (unsigned*)carve((size_t)e * 4);
    float*    val       = (float*)carve((size_t)e * 4);
    int*      gstart    = (int*)carve(65 * 4);
    float*    psum      = (float*)carve((size_t)NGRAPH_C * 300 * 4);
    short*    WpHi      = (short*)carve((size_t)10 * 20 * 64 * 8 * 2);
    short*    WpLo      = (short*)carve((size_t)10 * 20 * 64 * 8 * 2);

    const int* src = ei;
    const int* dst = ei + e;

    hipMemsetAsync(counts, 0, (size_t)n * 4, stream);
    hipMemsetAsync(fill, 0, (size_t)n * 4, stream);
    hipMemsetAsync(psum, 0, (size_t)NGRAPH_C * 300 * 4, stream);

    int eb = (e + 255) / 256;
    int nb256 = (n + 255) / 256;
    int NB = (n + 1023) / 1024;  // 98

    k_count<<<eb, 256, 0, stream>>>(dst, counts, e);
    k_dinv<<<nb256, 256, 0, stream>>>(counts, dinv, n);
    k_blocksum<<<NB, 256, 0, stream>>>(counts, partials, n);
    k_scanpartials<<<1, 128, 0, stream>>>(partials, NB);
    k_scanblock<<<NB, 256, 0, stream>>>(counts, partials, row_start, n);
    k_fill<<<eb, 256, 0, stream>>>(src, dst, row_start, fill, colb, val, dinv, e);
    k_gstart<<<1, 128, 0, stream>>>(batch, gstart, n, NGRAPH_C);
    k_packW<<<(10 * 20 * 64 + 255) / 256, 256, 0, stream>>>(W, WpHi, WpLo);

    int gb = (n75 + 255) / 256;
    k_embed<<<gb, 256, 0, stream>>>(x, (const float4*)at, (const float4*)wt, (float4*)h, n75);

    dim3 ggrid((n + G_BM - 1) / G_BM, 2);
    for (int hop = 0; hop < 3; ++hop) {
        k_gemm_mfma<<<ggrid, 256, 0, stream>>>(h, WpHi, WpLo, hw, n);
        k_agg<<<gb, 256, 0, stream>>>((const float4*)hw, dinv, row_start, colb, val,
                                      (const float4*)b, (float4*)h, n);
    }

    k_pool<<<NGRAPH_C * 8, 256, 0, stream>>>(h, gstart, psum);
    k_div<<<(NGRAPH_C * 300 + 255) / 256, 256, 0, stream>>>(psum, gstart, (float*)d_out);
}

// Round 3
// 1017.212 us; speedup vs baseline: 3.0314x; 1.1916x over previous
//
#include <hip/hip_runtime.h>
#include <hip/hip_bf16.h>

#define N_NODES_C 100000
#define N_EDGES_C 800000
#define DIM_C 300
#define PADD 320          // padded feature dim (10 k-tiles of 32)
#define CH 40             // 16B bf16x8 chunks per row (320/8)
#define NGRAPH_C 64

typedef short bf16x8 __attribute__((ext_vector_type(8)));
typedef float f32x4 __attribute__((ext_vector_type(4)));
typedef int   i32x4 __attribute__((ext_vector_type(4)));

// ---- bf16 helpers (manual RN-even) ----
__device__ __forceinline__ unsigned f_as_u(float f) { union { float f; unsigned u; } c; c.f = f; return c.u; }
__device__ __forceinline__ float u_as_f(unsigned u) { union { unsigned u; float f; } c; c.u = u; return c.f; }
__device__ __forceinline__ short f2bf_rn(float f) {
    unsigned u = f_as_u(f);
    unsigned r = (u + 0x7FFFu + ((u >> 16) & 1u)) >> 16;
    return (short)r;
}
__device__ __forceinline__ float bf2f(short s) { return u_as_f(((unsigned)(unsigned short)s) << 16); }

// ---------------- degree count ----------------
__global__ __launch_bounds__(256) void k_count(const int* __restrict__ dst,
                                               unsigned* __restrict__ counts, int e) {
    int i = blockIdx.x * 256 + threadIdx.x;
    if (i < e) atomicAdd(&counts[dst[i]], 1u);
}

__global__ __launch_bounds__(256) void k_dinv(const unsigned* __restrict__ counts,
                                              float* __restrict__ dinv, int n) {
    int i = blockIdx.x * 256 + threadIdx.x;
    if (i < n) dinv[i] = rsqrtf((float)(counts[i] + 1u));  // +1 self loop
}

// ---------------- 2-level exclusive scan over counts ----------------
__global__ __launch_bounds__(256) void k_blocksum(const unsigned* __restrict__ counts,
                                                  unsigned* __restrict__ partials, int n) {
    __shared__ unsigned s[256];
    int base = blockIdx.x * 1024;
    unsigned sum = 0;
    for (int j = threadIdx.x; j < 1024; j += 256) {
        int i = base + j;
        sum += (i < n) ? counts[i] : 0u;
    }
    s[threadIdx.x] = sum;
    __syncthreads();
    for (int off = 128; off > 0; off >>= 1) {
        if (threadIdx.x < (unsigned)off) s[threadIdx.x] += s[threadIdx.x + off];
        __syncthreads();
    }
    if (threadIdx.x == 0) partials[blockIdx.x] = s[0];
}

__global__ __launch_bounds__(128) void k_scanpartials(unsigned* __restrict__ partials, int nb) {
    __shared__ unsigned s[128];
    int t = threadIdx.x;
    s[t] = (t < nb) ? partials[t] : 0u;
    __syncthreads();
    if (t == 0) {
        unsigned run = 0;
        for (int i = 0; i < nb; ++i) { unsigned v = s[i]; s[i] = run; run += v; }
    }
    __syncthreads();
    if (t < nb) partials[t] = s[t];
}

__global__ __launch_bounds__(256) void k_scanblock(const unsigned* __restrict__ counts,
                                                   const unsigned* __restrict__ partials,
                                                   unsigned* __restrict__ row_start, int n) {
    __shared__ unsigned s[256];
    int base = blockIdx.x * 1024;
    int t = threadIdx.x;
    unsigned v[4];
    unsigned tsum = 0;
#pragma unroll
    for (int j = 0; j < 4; ++j) {
        int i = base + t * 4 + j;
        v[j] = (i < n) ? counts[i] : 0u;
        tsum += v[j];
    }
    s[t] = tsum;
    __syncthreads();
    for (int off = 1; off < 256; off <<= 1) {
        unsigned x = (t >= off) ? s[t - off] : 0u;
        __syncthreads();
        s[t] += x;
        __syncthreads();
    }
    unsigned excl = (t > 0 ? s[t - 1] : 0u) + partials[blockIdx.x];
#pragma unroll
    for (int j = 0; j < 4; ++j) {
        int i = base + t * 4 + j;
        if (i < n) {
            row_start[i] = excl;
            excl += v[j];
            if (i == n - 1) row_start[n] = excl;
        }
    }
}

// ---------------- CSR fill ----------------
__global__ __launch_bounds__(256) void k_fill(const int* __restrict__ src, const int* __restrict__ dst,
                                              const unsigned* __restrict__ row_start,
                                              unsigned* __restrict__ fill,
                                              unsigned* __restrict__ col, float* __restrict__ val,
                                              const float* __restrict__ dinv, int e) {
    int i = blockIdx.x * 256 + threadIdx.x;
    if (i >= e) return;
    int d = dst[i], s0 = src[i];
    unsigned pos = row_start[d] + atomicAdd(&fill[d], 1u);
    col[pos] = (unsigned)s0;
    val[pos] = dinv[s0] * dinv[d];
}

// ---------------- embedding -> bf16 padded rows ----------------
__global__ __launch_bounds__(256) void k_embed(const int* __restrict__ x,
                                               const float* __restrict__ at,
                                               const float* __restrict__ wt,
                                               short* __restrict__ h, int n) {
    int idx = blockIdx.x * 256 + threadIdx.x;
    if (idx >= n * CH) return;
    int i = idx / CH;
    int c8 = idx - i * CH;
    int bc = c8 * 8;
    bf16x8 out;
    if (c8 >= 38) {
#pragma unroll
        for (int j = 0; j < 8; ++j) out[j] = 0;
    } else {
        int a = x[2 * i], w = x[2 * i + 1];
        float v[8];
        if (c8 < 37) {
            const float4* pa = (const float4*)&at[a * 300 + bc];
            const float4* pw = (const float4*)&wt[w * 300 + bc];
            float4 a0 = pa[0], a1 = pa[1], w0 = pw[0], w1 = pw[1];
            v[0] = a0.x + w0.x; v[1] = a0.y + w0.y; v[2] = a0.z + w0.z; v[3] = a0.w + w0.w;
            v[4] = a1.x + w1.x; v[5] = a1.y + w1.y; v[6] = a1.z + w1.z; v[7] = a1.w + w1.w;
        } else {
#pragma unroll
            for (int j = 0; j < 8; ++j) {
                int c = bc + j;
                v[j] = (c < 300) ? (at[a * 300 + c] + wt[w * 300 + c]) : 0.f;
            }
        }
#pragma unroll
        for (int j = 0; j < 8; ++j) out[j] = f2bf_rn(v[j]);
    }
    *(bf16x8*)&h[(size_t)i * PADD + bc] = out;
}

// ---------------- W pack: fragment-layout bf16 hi/lo, padded 320x320 ----------------
__global__ __launch_bounds__(256) void k_packW(const float* __restrict__ W,
                                               short* __restrict__ WpHi, short* __restrict__ WpLo) {
    int t = blockIdx.x * 256 + threadIdx.x;
    if (t >= 10 * 20 * 64) return;
    int lane = t & 63;
    int frag = t >> 6;           // kt*20 + nt
    int kt = frag / 20;
    int nt = frag - kt * 20;
    int kbase = kt * 32 + (lane >> 4) * 8;
    int ncol = nt * 16 + (lane & 15);
    bf16x8 vh, vl;
#pragma unroll
    for (int j = 0; j < 8; ++j) {
        int k = kbase + j;
        float v = (k < 300 && ncol < 300) ? W[k * 300 + ncol] : 0.f;
        short hi = f2bf_rn(v);
        vh[j] = hi;
        vl[j] = f2bf_rn(v - bf2f(hi));
    }
    *(bf16x8*)&WpHi[(size_t)t * 8] = vh;
    *(bf16x8*)&WpLo[(size_t)t * 8] = vl;
}

// ---------------- GEMM: Cb[M,320](bf16) = A[M,320](bf16) * W (hi/lo 2-pass) ----------------
#define G_BM 128
#define LDS_RS 40  // LDS row stride in shorts (32 + 8 pad: 2-way max aliasing = free)

__global__ __launch_bounds__(256) void k_gemm2(const short* __restrict__ A,
                                               const short* __restrict__ WpHi,
                                               const short* __restrict__ WpLo,
                                               short* __restrict__ Cb, int M) {
    __shared__ short As[G_BM * LDS_RS];
    const int tid = threadIdx.x;
    const int wave = tid >> 6;
    const int lane = tid & 63;
    const int r = lane & 15;
    const int quad = lane >> 4;
    const int bm0 = blockIdx.x * G_BM;
    const int bn = blockIdx.y;  // 0..1

    f32x4 acc[2][10];
#pragma unroll
    for (int mi = 0; mi < 2; ++mi)
#pragma unroll
        for (int nt = 0; nt < 10; ++nt) acc[mi][nt] = (f32x4){0.f, 0.f, 0.f, 0.f};

    for (int kt = 0; kt < 10; ++kt) {
        const int k0 = kt * 32;
        // stage A[bm0..+128][k0..+32] bf16 -> LDS (no conversion)
#pragma unroll
        for (int it = 0; it < 2; ++it) {
            int idx = it * 256 + tid;        // 0..511
            int row = idx >> 2, q = idx & 3;
            int grow = bm0 + row;
            bf16x8 v;
            if (grow < M) {
                v = *(const bf16x8*)&A[(size_t)grow * PADD + k0 + q * 8];
            } else {
#pragma unroll
                for (int j = 0; j < 8; ++j) v[j] = 0;
            }
            *(bf16x8*)&As[row * LDS_RS + q * 8] = v;
        }
        __syncthreads();

        bf16x8 ah[2];
#pragma unroll
        for (int mi = 0; mi < 2; ++mi)
            ah[mi] = *(const bf16x8*)&As[(wave * 32 + mi * 16 + r) * LDS_RS + quad * 8];

#pragma unroll
        for (int nt = 0; nt < 10; ++nt) {
            int ntg = bn * 10 + nt;
            size_t fidx = ((size_t)(kt * 20 + ntg) * 64 + lane) * 8;
            bf16x8 bh = *(const bf16x8*)&WpHi[fidx];
            bf16x8 bl = *(const bf16x8*)&WpLo[fidx];
#pragma unroll
            for (int mi = 0; mi < 2; ++mi) {
                acc[mi][nt] = __builtin_amdgcn_mfma_f32_16x16x32_bf16(ah[mi], bh, acc[mi][nt], 0, 0, 0);
                acc[mi][nt] = __builtin_amdgcn_mfma_f32_16x16x32_bf16(ah[mi], bl, acc[mi][nt], 0, 0, 0);
            }
        }
        __syncthreads();
    }

    // epilogue: C/D layout col=lane&15, row=quad*4+reg; write bf16 (incl. zero pad cols)
#pragma unroll
    for (int mi = 0; mi < 2; ++mi) {
#pragma unroll
        for (int nt = 0; nt < 10; ++nt) {
            int col = bn * 160 + nt * 16 + r;
            int row0 = bm0 + wave * 32 + mi * 16 + quad * 4;
            f32x4 c = acc[mi][nt];
#pragma unroll
            for (int reg = 0; reg < 4; ++reg) {
                int row = row0 + reg;
                if (row < M) Cb[(size_t)row * PADD + col] = f2bf_rn(c[reg]);
            }
        }
    }
}

// ---------------- aggregation: h = bf16( b + D^-1/2 A D^-1/2 hw ), nontemporal out ----------------
__global__ __launch_bounds__(256) void k_agg(const short* __restrict__ hw,
                                             const float* __restrict__ dinv,
                                             const unsigned* __restrict__ row_start,
                                             const unsigned* __restrict__ col,
                                             const float* __restrict__ val,
                                             const float* __restrict__ b,
                                             short* __restrict__ hout, int n) {
    int idx = blockIdx.x * 256 + threadIdx.x;
    if (idx >= n * CH) return;
    int i = idx / CH;
    int c8 = idx - i * CH;
    int bc = c8 * 8;

    float acc[8];
    if (c8 < 37) {
        const float4* pb = (const float4*)&b[bc];
        float4 b0 = pb[0], b1 = pb[1];
        acc[0] = b0.x; acc[1] = b0.y; acc[2] = b0.z; acc[3] = b0.w;
        acc[4] = b1.x; acc[5] = b1.y; acc[6] = b1.z; acc[7] = b1.w;
    } else {
#pragma unroll
        for (int j = 0; j < 8; ++j) {
            int c = bc + j;
            acc[j] = (c < 300) ? b[c] : 0.f;
        }
    }

    float di = dinv[i];
    float sn = di * di;
    bf16x8 sv = *(const bf16x8*)&hw[(size_t)i * PADD + bc];
#pragma unroll
    for (int j = 0; j < 8; ++j) acc[j] += sn * bf2f(sv[j]);

    unsigned e0 = row_start[i], e1 = row_start[i + 1];
    unsigned e = e0;
    for (; e + 2 <= e1; e += 2) {
        unsigned c0 = col[e], c1 = col[e + 1];
        float v0 = val[e], v1 = val[e + 1];
        bf16x8 m0 = *(const bf16x8*)&hw[(size_t)c0 * PADD + bc];
        bf16x8 m1 = *(const bf16x8*)&hw[(size_t)c1 * PADD + bc];
#pragma unroll
        for (int j = 0; j < 8; ++j) acc[j] += v0 * bf2f(m0[j]) + v1 * bf2f(m1[j]);
    }
    if (e < e1) {
        unsigned c0 = col[e];
        float v0 = val[e];
        bf16x8 m0 = *(const bf16x8*)&hw[(size_t)c0 * PADD + bc];
#pragma unroll
        for (int j = 0; j < 8; ++j) acc[j] += v0 * bf2f(m0[j]);
    }

    bf16x8 out;
#pragma unroll
    for (int j = 0; j < 8; ++j) out[j] = f2bf_rn(acc[j]);
    union { bf16x8 s; i32x4 i; } cv;
    cv.s = out;
    __builtin_nontemporal_store(cv.i, (i32x4*)&hout[(size_t)i * PADD + bc]);
}

// ---------------- graph boundaries (batch sorted) ----------------
__global__ __launch_bounds__(128) void k_gstart(const int* __restrict__ batch,
                                                int* __restrict__ gstart, int n, int ngraph) {
    int g = threadIdx.x;
    if (g > ngraph) return;
    if (g == ngraph) { gstart[g] = n; return; }
    int lo = 0, hi = n;
    while (lo < hi) {
        int mid = (lo + hi) >> 1;
        if (batch[mid] < g) lo = mid + 1; else hi = mid;
    }
    gstart[g] = lo;
}

// ---------------- pool: per-graph sums over bf16 h ----------------
__global__ __launch_bounds__(256) void k_pool(const short* __restrict__ h,
                                              const int* __restrict__ gstart,
                                              float* __restrict__ psum) {
    int g = blockIdx.x >> 3;
    int chunk = blockIdx.x & 7;
    int lo = gstart[g], hi = gstart[g + 1];
    int cnt = hi - lo;
    int s = lo + (int)((long)cnt * chunk / 8);
    int e2 = lo + (int)((long)cnt * (chunk + 1) / 8);
    for (int c = threadIdx.x; c < 300; c += 256) {
        float acc = 0.f;
        for (int i = s; i < e2; ++i) acc += bf2f(h[(size_t)i * PADD + c]);
        atomicAdd(&psum[g * 300 + c], acc);
    }
}

__global__ __launch_bounds__(256) void k_div(const float* __restrict__ psum,
                                             const int* __restrict__ gstart,
                                             float* __restrict__ out) {
    int j = blockIdx.x * 256 + threadIdx.x;
    if (j >= NGRAPH_C * 300) return;
    int g = j / 300;
    int c2 = gstart[g + 1] - gstart[g];
    out[j] = psum[j] / (float)(c2 > 0 ? c2 : 1);
}

// ---------------- launch ----------------
extern "C" void kernel_launch(void* const* d_in, const int* in_sizes, int n_in,
                              void* d_out, int out_size, void* d_ws, size_t ws_size,
                              hipStream_t stream) {
    const int*   x     = (const int*)d_in[0];
    const int*   ei    = (const int*)d_in[1];
    const int*   batch = (const int*)d_in[2];
    const float* at    = (const float*)d_in[3];
    const float* wt    = (const float*)d_in[4];
    const float* W     = (const float*)d_in[5];
    const float* b     = (const float*)d_in[6];

    const int n = in_sizes[0] / 2;   // 100000
    const int e = in_sizes[1] / 2;   // 800000

    // workspace carve (256B aligned)
    char* ws = (char*)d_ws;
    size_t off = 0;
    auto carve = [&](size_t bytes) {
        void* p = ws + off;
        off += (bytes + 255) & ~(size_t)255;
        return p;
    };
    short*    h         = (short*)carve((size_t)n * PADD * 2);
    short*    hw        = (short*)carve((size_t)n * PADD * 2);
    float*    dinv      = (float*)carve((size_t)n * 4);
    unsigned* counts    = (unsigned*)carve((size_t)n * 4);
    unsigned* fill      = (unsigned*)carve((size_t)n * 4);
    unsigned* row_start = (unsigned*)carve((size_t)(n + 1) * 4);
    unsigned* partials  = (unsigned*)carve(1024 * 4);
    unsigned* colb      = (unsigned*)carve((size_t)e * 4);
    float*    val       = (float*)carve((size_t)e * 4);
    int*      gstart    = (int*)carve(65 * 4);
    float*    psum      = (float*)carve((size_t)NGRAPH_C * 300 * 4);
    short*    WpHi      = (short*)carve((size_t)10 * 20 * 64 * 8 * 2);
    short*    WpLo      = (short*)carve((size_t)10 * 20 * 64 * 8 * 2);

    const int* src = ei;
    const int* dst = ei + e;

    hipMemsetAsync(counts, 0, (size_t)n * 4, stream);
    hipMemsetAsync(fill, 0, (size_t)n * 4, stream);
    hipMemsetAsync(psum, 0, (size_t)NGRAPH_C * 300 * 4, stream);

    int eb = (e + 255) / 256;
    int nb256 = (n + 255) / 256;
    int NB = (n + 1023) / 1024;  // 98

    k_count<<<eb, 256, 0, stream>>>(dst, counts, e);
    k_dinv<<<nb256, 256, 0, stream>>>(counts, dinv, n);
    k_blocksum<<<NB, 256, 0, stream>>>(counts, partials, n);
    k_scanpartials<<<1, 128, 0, stream>>>(partials, NB);
    k_scanblock<<<NB, 256, 0, stream>>>(counts, partials, row_start, n);
    k_fill<<<eb, 256, 0, stream>>>(src, dst, row_start, fill, colb, val, dinv, e);
    k_gstart<<<1, 128, 0, stream>>>(batch, gstart, n, NGRAPH_C);
    k_packW<<<(10 * 20 * 64 + 255) / 256, 256, 0, stream>>>(W, WpHi, WpLo);

    int gb = (n * CH + 255) / 256;
    k_embed<<<gb, 256, 0, stream>>>(x, at, wt, h, n);

    dim3 ggrid((n + G_BM - 1) / G_BM, 2);
    for (int hop = 0; hop < 3; ++hop) {
        k_gemm2<<<ggrid, 256, 0, stream>>>(h, WpHi, WpLo, hw, n);
        k_agg<<<gb, 256, 0, stream>>>(hw, dinv, row_start, colb, val, b, h, n);
    }

    k_pool<<<NGRAPH_C * 8, 256, 0, stream>>>(h, gstart, psum);
    k_div<<<(NGRAPH_C * 300 + 255) / 256, 256, 0, stream>>>(psum, gstart, (float*)d_out);
}

// Round 4
// 882.494 us; speedup vs baseline: 3.4942x; 1.1527x over previous
//
#include <hip/hip_runtime.h>
#include <hip/hip_bf16.h>

#define N_NODES_C 100000
#define N_EDGES_C 800000
#define DIM_C 300
#define PADD 320          // padded feature dim (10 k-tiles of 32)
#define CH 40             // 16B bf16x8 chunks per row (320/8)
#define NGRAPH_C 64

typedef short bf16x8 __attribute__((ext_vector_type(8)));
typedef float f32x4 __attribute__((ext_vector_type(4)));

// ---- bf16 helpers (manual RN-even) ----
__device__ __forceinline__ unsigned f_as_u(float f) { union { float f; unsigned u; } c; c.f = f; return c.u; }
__device__ __forceinline__ float u_as_f(unsigned u) { union { unsigned u; float f; } c; c.u = u; return c.f; }
__device__ __forceinline__ short f2bf_rn(float f) {
    unsigned u = f_as_u(f);
    unsigned r = (u + 0x7FFFu + ((u >> 16) & 1u)) >> 16;
    return (short)r;
}
__device__ __forceinline__ float bf2f(short s) { return u_as_f(((unsigned)(unsigned short)s) << 16); }

// ---------------- degree count ----------------
__global__ __launch_bounds__(256) void k_count(const int* __restrict__ dst,
                                               unsigned* __restrict__ counts, int e) {
    int i = blockIdx.x * 256 + threadIdx.x;
    if (i < e) atomicAdd(&counts[dst[i]], 1u);
}

__global__ __launch_bounds__(256) void k_dinv(const unsigned* __restrict__ counts,
                                              float* __restrict__ dinv, int n) {
    int i = blockIdx.x * 256 + threadIdx.x;
    if (i < n) dinv[i] = rsqrtf((float)(counts[i] + 1u));  // +1 self loop
}

// ---------------- 2-level exclusive scan over counts ----------------
__global__ __launch_bounds__(256) void k_blocksum(const unsigned* __restrict__ counts,
                                                  unsigned* __restrict__ partials, int n) {
    __shared__ unsigned s[256];
    int base = blockIdx.x * 1024;
    unsigned sum = 0;
    for (int j = threadIdx.x; j < 1024; j += 256) {
        int i = base + j;
        sum += (i < n) ? counts[i] : 0u;
    }
    s[threadIdx.x] = sum;
    __syncthreads();
    for (int off = 128; off > 0; off >>= 1) {
        if (threadIdx.x < (unsigned)off) s[threadIdx.x] += s[threadIdx.x + off];
        __syncthreads();
    }
    if (threadIdx.x == 0) partials[blockIdx.x] = s[0];
}

__global__ __launch_bounds__(128) void k_scanpartials(unsigned* __restrict__ partials, int nb) {
    __shared__ unsigned s[128];
    int t = threadIdx.x;
    s[t] = (t < nb) ? partials[t] : 0u;
    __syncthreads();
    if (t == 0) {
        unsigned run = 0;
        for (int i = 0; i < nb; ++i) { unsigned v = s[i]; s[i] = run; run += v; }
    }
    __syncthreads();
    if (t < nb) partials[t] = s[t];
}

__global__ __launch_bounds__(256) void k_scanblock(const unsigned* __restrict__ counts,
                                                   const unsigned* __restrict__ partials,
                                                   unsigned* __restrict__ row_start, int n) {
    __shared__ unsigned s[256];
    int base = blockIdx.x * 1024;
    int t = threadIdx.x;
    unsigned v[4];
    unsigned tsum = 0;
#pragma unroll
    for (int j = 0; j < 4; ++j) {
        int i = base + t * 4 + j;
        v[j] = (i < n) ? counts[i] : 0u;
        tsum += v[j];
    }
    s[t] = tsum;
    __syncthreads();
    for (int off = 1; off < 256; off <<= 1) {
        unsigned x = (t >= off) ? s[t - off] : 0u;
        __syncthreads();
        s[t] += x;
        __syncthreads();
    }
    unsigned excl = (t > 0 ? s[t - 1] : 0u) + partials[blockIdx.x];
#pragma unroll
    for (int j = 0; j < 4; ++j) {
        int i = base + t * 4 + j;
        if (i < n) {
            row_start[i] = excl;
            excl += v[j];
            if (i == n - 1) row_start[n] = excl;
        }
    }
}

// ---------------- CSR fill ----------------
__global__ __launch_bounds__(256) void k_fill(const int* __restrict__ src, const int* __restrict__ dst,
                                              const unsigned* __restrict__ row_start,
                                              unsigned* __restrict__ fill,
                                              unsigned* __restrict__ col, float* __restrict__ val,
                                              const float* __restrict__ dinv, int e) {
    int i = blockIdx.x * 256 + threadIdx.x;
    if (i >= e) return;
    int d = dst[i], s0 = src[i];
    unsigned pos = row_start[d] + atomicAdd(&fill[d], 1u);
    col[pos] = (unsigned)s0;
    val[pos] = dinv[s0] * dinv[d];
}

// ---------------- embedding -> bf16 padded rows ----------------
__global__ __launch_bounds__(256) void k_embed(const int* __restrict__ x,
                                               const float* __restrict__ at,
                                               const float* __restrict__ wt,
                                               short* __restrict__ h, int n) {
    int idx = blockIdx.x * 256 + threadIdx.x;
    if (idx >= n * CH) return;
    int i = idx / CH;
    int c8 = idx - i * CH;
    int bc = c8 * 8;
    bf16x8 out;
    if (c8 >= 38) {
#pragma unroll
        for (int j = 0; j < 8; ++j) out[j] = 0;
    } else {
        int a = x[2 * i], w = x[2 * i + 1];
        float v[8];
        if (c8 < 37) {
            const float4* pa = (const float4*)&at[a * 300 + bc];
            const float4* pw = (const float4*)&wt[w * 300 + bc];
            float4 a0 = pa[0], a1 = pa[1], w0 = pw[0], w1 = pw[1];
            v[0] = a0.x + w0.x; v[1] = a0.y + w0.y; v[2] = a0.z + w0.z; v[3] = a0.w + w0.w;
            v[4] = a1.x + w1.x; v[5] = a1.y + w1.y; v[6] = a1.z + w1.z; v[7] = a1.w + w1.w;
        } else {
#pragma unroll
            for (int j = 0; j < 8; ++j) {
                int c = bc + j;
                v[j] = (c < 300) ? (at[a * 300 + c] + wt[w * 300 + c]) : 0.f;
            }
        }
#pragma unroll
        for (int j = 0; j < 8; ++j) out[j] = f2bf_rn(v[j]);
    }
    *(bf16x8*)&h[(size_t)i * PADD + bc] = out;
}

// ---------------- W pack: fragment-layout bf16 hi/lo, padded 320x320 ----------------
__global__ __launch_bounds__(256) void k_packW(const float* __restrict__ W,
                                               short* __restrict__ WpHi, short* __restrict__ WpLo) {
    int t = blockIdx.x * 256 + threadIdx.x;
    if (t >= 10 * 20 * 64) return;
    int lane = t & 63;
    int frag = t >> 6;           // kt*20 + nt
    int kt = frag / 20;
    int nt = frag - kt * 20;
    int kbase = kt * 32 + (lane >> 4) * 8;
    int ncol = nt * 16 + (lane & 15);
    bf16x8 vh, vl;
#pragma unroll
    for (int j = 0; j < 8; ++j) {
        int k = kbase + j;
        float v = (k < 300 && ncol < 300) ? W[k * 300 + ncol] : 0.f;
        short hi = f2bf_rn(v);
        vh[j] = hi;
        vl[j] = f2bf_rn(v - bf2f(hi));
    }
    *(bf16x8*)&WpHi[(size_t)t * 8] = vh;
    *(bf16x8*)&WpLo[(size_t)t * 8] = vl;
}

// ---------------- GEMM: Cb[M,320](bf16) = A[M,320](bf16) * W (hi/lo 2-pass) ----------------
#define G_BM 128
#define LDS_RS 40  // LDS row stride in shorts (32 + 8 pad: 2-way max aliasing = free)

__global__ __launch_bounds__(256) void k_gemm2(const short* __restrict__ A,
                                               const short* __restrict__ WpHi,
                                               const short* __restrict__ WpLo,
                                               short* __restrict__ Cb, int M) {
    __shared__ short As[G_BM * LDS_RS];
    const int tid = threadIdx.x;
    const int wave = tid >> 6;
    const int lane = tid & 63;
    const int r = lane & 15;
    const int quad = lane >> 4;
    const int bm0 = blockIdx.x * G_BM;
    const int bn = blockIdx.y;  // 0..1

    f32x4 acc[2][10];
#pragma unroll
    for (int mi = 0; mi < 2; ++mi)
#pragma unroll
        for (int nt = 0; nt < 10; ++nt) acc[mi][nt] = (f32x4){0.f, 0.f, 0.f, 0.f};

    for (int kt = 0; kt < 10; ++kt) {
        const int k0 = kt * 32;
        // stage A[bm0..+128][k0..+32] bf16 -> LDS (no conversion)
#pragma unroll
        for (int it = 0; it < 2; ++it) {
            int idx = it * 256 + tid;        // 0..511
            int row = idx >> 2, q = idx & 3;
            int grow = bm0 + row;
            bf16x8 v;
            if (grow < M) {
                v = *(const bf16x8*)&A[(size_t)grow * PADD + k0 + q * 8];
            } else {
#pragma unroll
                for (int j = 0; j < 8; ++j) v[j] = 0;
            }
            *(bf16x8*)&As[row * LDS_RS + q * 8] = v;
        }
        __syncthreads();

        bf16x8 ah[2];
#pragma unroll
        for (int mi = 0; mi < 2; ++mi)
            ah[mi] = *(const bf16x8*)&As[(wave * 32 + mi * 16 + r) * LDS_RS + quad * 8];

#pragma unroll
        for (int nt = 0; nt < 10; ++nt) {
            int ntg = bn * 10 + nt;
            size_t fidx = ((size_t)(kt * 20 + ntg) * 64 + lane) * 8;
            bf16x8 bh = *(const bf16x8*)&WpHi[fidx];
            bf16x8 bl = *(const bf16x8*)&WpLo[fidx];
#pragma unroll
            for (int mi = 0; mi < 2; ++mi) {
                acc[mi][nt] = __builtin_amdgcn_mfma_f32_16x16x32_bf16(ah[mi], bh, acc[mi][nt], 0, 0, 0);
                acc[mi][nt] = __builtin_amdgcn_mfma_f32_16x16x32_bf16(ah[mi], bl, acc[mi][nt], 0, 0, 0);
            }
        }
        __syncthreads();
    }

    // epilogue: C/D layout col=lane&15, row=quad*4+reg; write bf16 (incl. zero pad cols)
#pragma unroll
    for (int mi = 0; mi < 2; ++mi) {
#pragma unroll
        for (int nt = 0; nt < 10; ++nt) {
            int col = bn * 160 + nt * 16 + r;
            int row0 = bm0 + wave * 32 + mi * 16 + quad * 4;
            f32x4 c = acc[mi][nt];
#pragma unroll
            for (int reg = 0; reg < 4; ++reg) {
                int row = row0 + reg;
                if (row < M) Cb[(size_t)row * PADD + col] = f2bf_rn(c[reg]);
            }
        }
    }
}

// ---------------- aggregation: h = bf16( b + D^-1/2 A D^-1/2 hw ) ----------------
__global__ __launch_bounds__(256) void k_agg(const short* __restrict__ hw,
                                             const float* __restrict__ dinv,
                                             const unsigned* __restrict__ row_start,
                                             const unsigned* __restrict__ col,
                                             const float* __restrict__ val,
                                             const float* __restrict__ b,
                                             short* __restrict__ hout, int n) {
    int idx = blockIdx.x * 256 + threadIdx.x;
    if (idx >= n * CH) return;
    int i = idx / CH;
    int c8 = idx - i * CH;
    int bc = c8 * 8;

    float acc[8];
    if (c8 < 37) {
        const float4* pb = (const float4*)&b[bc];
        float4 b0 = pb[0], b1 = pb[1];
        acc[0] = b0.x; acc[1] = b0.y; acc[2] = b0.z; acc[3] = b0.w;
        acc[4] = b1.x; acc[5] = b1.y; acc[6] = b1.z; acc[7] = b1.w;
    } else {
#pragma unroll
        for (int j = 0; j < 8; ++j) {
            int c = bc + j;
            acc[j] = (c < 300) ? b[c] : 0.f;
        }
    }

    float di = dinv[i];
    float sn = di * di;
    bf16x8 sv = *(const bf16x8*)&hw[(size_t)i * PADD + bc];
#pragma unroll
    for (int j = 0; j < 8; ++j) acc[j] += sn * bf2f(sv[j]);

    unsigned e0 = row_start[i], e1 = row_start[i + 1];
    unsigned e = e0;
    for (; e + 2 <= e1; e += 2) {
        unsigned c0 = col[e], c1 = col[e + 1];
        float v0 = val[e], v1 = val[e + 1];
        bf16x8 m0 = *(const bf16x8*)&hw[(size_t)c0 * PADD + bc];
        bf16x8 m1 = *(const bf16x8*)&hw[(size_t)c1 * PADD + bc];
#pragma unroll
        for (int j = 0; j < 8; ++j) acc[j] += v0 * bf2f(m0[j]) + v1 * bf2f(m1[j]);
    }
    if (e < e1) {
        unsigned c0 = col[e];
        float v0 = val[e];
        bf16x8 m0 = *(const bf16x8*)&hw[(size_t)c0 * PADD + bc];
#pragma unroll
        for (int j = 0; j < 8; ++j) acc[j] += v0 * bf2f(m0[j]);
    }

    bf16x8 out;
#pragma unroll
    for (int j = 0; j < 8; ++j) out[j] = f2bf_rn(acc[j]);
    *(bf16x8*)&hout[(size_t)i * PADD + bc] = out;
}

// ---------------- graph boundaries (batch sorted) ----------------
__global__ __launch_bounds__(128) void k_gstart(const int* __restrict__ batch,
                                                int* __restrict__ gstart, int n, int ngraph) {
    int g = threadIdx.x;
    if (g > ngraph) return;
    if (g == ngraph) { gstart[g] = n; return; }
    int lo = 0, hi = n;
    while (lo < hi) {
        int mid = (lo + hi) >> 1;
        if (batch[mid] < g) lo = mid + 1; else hi = mid;
    }
    gstart[g] = lo;
}

// ---------------- pool: 64 graphs x 16 chunks, vectorized row-major reads ----------------
// thread t: column-chunk c8 = t%40 (16B bf16x8), row-lane rl = t/40 (6 rows in flight)
__global__ __launch_bounds__(256) void k_pool(const short* __restrict__ h,
                                              const int* __restrict__ gstart,
                                              float* __restrict__ psum) {
    __shared__ float red[6][40][8];
    int g = blockIdx.x >> 4;
    int chunk = blockIdx.x & 15;
    int lo = gstart[g], hi = gstart[g + 1];
    int cnt = hi - lo;
    int s = lo + (int)((long)cnt * chunk / 16);
    int e2 = lo + (int)((long)cnt * (chunk + 1) / 16);
    int t = threadIdx.x;
    int c8 = t % 40;
    int rl = t / 40;                 // 0..6 (rl==6 lanes inactive)
    bool live = (rl < 6) && (c8 < 38);  // chunks 38,39 are all-zero pad

    float acc[8];
#pragma unroll
    for (int j = 0; j < 8; ++j) acc[j] = 0.f;

    if (live) {
        int r = s + rl;
        for (; r + 6 < e2; r += 12) {   // 2 independent 16B loads in flight
            bf16x8 v0 = *(const bf16x8*)&h[(size_t)r * PADD + c8 * 8];
            bf16x8 v1 = *(const bf16x8*)&h[(size_t)(r + 6) * PADD + c8 * 8];
#pragma unroll
            for (int j = 0; j < 8; ++j) acc[j] += bf2f(v0[j]) + bf2f(v1[j]);
        }
        if (r < e2) {
            bf16x8 v0 = *(const bf16x8*)&h[(size_t)r * PADD + c8 * 8];
#pragma unroll
            for (int j = 0; j < 8; ++j) acc[j] += bf2f(v0[j]);
        }
    }
    if (rl < 6) {
#pragma unroll
        for (int j = 0; j < 8; ++j) red[rl][c8][j] = acc[j];
    }
    __syncthreads();
    if (t < 38) {                    // rl==0, c8==t
        float s8[8];
#pragma unroll
        for (int j = 0; j < 8; ++j)
            s8[j] = red[0][t][j] + red[1][t][j] + red[2][t][j] +
                    red[3][t][j] + red[4][t][j] + red[5][t][j];
#pragma unroll
        for (int j = 0; j < 8; ++j) {
            int c = t * 8 + j;
            if (c < 300) atomicAdd(&psum[g * 300 + c], s8[j]);
        }
    }
}

__global__ __launch_bounds__(256) void k_div(const float* __restrict__ psum,
                                             const int* __restrict__ gstart,
                                             float* __restrict__ out) {
    int j = blockIdx.x * 256 + threadIdx.x;
    if (j >= NGRAPH_C * 300) return;
    int g = j / 300;
    int c2 = gstart[g + 1] - gstart[g];
    out[j] = psum[j] / (float)(c2 > 0 ? c2 : 1);
}

// ---------------- launch ----------------
extern "C" void kernel_launch(void* const* d_in, const int* in_sizes, int n_in,
                              void* d_out, int out_size, void* d_ws, size_t ws_size,
                              hipStream_t stream) {
    const int*   x     = (const int*)d_in[0];
    const int*   ei    = (const int*)d_in[1];
    const int*   batch = (const int*)d_in[2];
    const float* at    = (const float*)d_in[3];
    const float* wt    = (const float*)d_in[4];
    const float* W     = (const float*)d_in[5];
    const float* b     = (const float*)d_in[6];

    const int n = in_sizes[0] / 2;   // 100000
    const int e = in_sizes[1] / 2;   // 800000

    // workspace carve (256B aligned)
    char* ws = (char*)d_ws;
    size_t off = 0;
    auto carve = [&](size_t bytes) {
        void* p = ws + off;
        off += (bytes + 255) & ~(size_t)255;
        return p;
    };
    short*    h         = (short*)carve((size_t)n * PADD * 2);
    short*    hw        = (short*)carve((size_t)n * PADD * 2);
    float*    dinv      = (float*)carve((size_t)n * 4);
    unsigned* counts    = (unsigned*)carve((size_t)n * 4);
    unsigned* fill      = (unsigned*)carve((size_t)n * 4);
    unsigned* row_start = (unsigned*)carve((size_t)(n + 1) * 4);
    unsigned* partials  = (unsigned*)carve(1024 * 4);
    unsigned* colb      = (unsigned*)carve((size_t)e * 4);
    float*    val       = (float*)carve((size_t)e * 4);
    int*      gstart    = (int*)carve(65 * 4);
    float*    psum      = (float*)carve((size_t)NGRAPH_C * 300 * 4);
    short*    WpHi      = (short*)carve((size_t)10 * 20 * 64 * 8 * 2);
    short*    WpLo      = (short*)carve((size_t)10 * 20 * 64 * 8 * 2);

    const int* src = ei;
    const int* dst = ei + e;

    hipMemsetAsync(counts, 0, (size_t)n * 4, stream);
    hipMemsetAsync(fill, 0, (size_t)n * 4, stream);
    hipMemsetAsync(psum, 0, (size_t)NGRAPH_C * 300 * 4, stream);

    int eb = (e + 255) / 256;
    int nb256 = (n + 255) / 256;
    int NB = (n + 1023) / 1024;  // 98

    k_count<<<eb, 256, 0, stream>>>(dst, counts, e);
    k_dinv<<<nb256, 256, 0, stream>>>(counts, dinv, n);
    k_blocksum<<<NB, 256, 0, stream>>>(counts, partials, n);
    k_scanpartials<<<1, 128, 0, stream>>>(partials, NB);
    k_scanblock<<<NB, 256, 0, stream>>>(counts, partials, row_start, n);
    k_fill<<<eb, 256, 0, stream>>>(src, dst, row_start, fill, colb, val, dinv, e);
    k_gstart<<<1, 128, 0, stream>>>(batch, gstart, n, NGRAPH_C);
    k_packW<<<(10 * 20 * 64 + 255) / 256, 256, 0, stream>>>(W, WpHi, WpLo);

    int gb = (n * CH + 255) / 256;
    k_embed<<<gb, 256, 0, stream>>>(x, at, wt, h, n);

    dim3 ggrid((n + G_BM - 1) / G_BM, 2);
    for (int hop = 0; hop < 3; ++hop) {
        k_gemm2<<<ggrid, 256, 0, stream>>>(h, WpHi, WpLo, hw, n);
        k_agg<<<gb, 256, 0, stream>>>(hw, dinv, row_start, colb, val, b, h, n);
    }

    k_pool<<<NGRAPH_C * 16, 256, 0, stream>>>(h, gstart, psum);
    k_div<<<(NGRAPH_C * 300 + 255) / 256, 256, 0, stream>>>(psum, gstart, (float*)d_out);
}

// Round 5
// 756.223 us; speedup vs baseline: 4.0776x; 1.1670x over previous
//
#include <hip/hip_runtime.h>
#include <hip/hip_bf16.h>

#define N_NODES_C 100000
#define N_EDGES_C 800000
#define DIM_C 300
#define PADD 320          // padded feature dim (10 k-tiles of 32)
#define CH 40             // 16B bf16x8 chunks per row (320/8)
#define NGRAPH_C 64

typedef short bf16x8 __attribute__((ext_vector_type(8)));
typedef float f32x4 __attribute__((ext_vector_type(4)));
typedef float f32x16 __attribute__((ext_vector_type(16)));

// ---- bf16 helpers (manual RN-even) ----
__device__ __forceinline__ unsigned f_as_u(float f) { union { float f; unsigned u; } c; c.f = f; return c.u; }
__device__ __forceinline__ float u_as_f(unsigned u) { union { unsigned u; float f; } c; c.u = u; return c.f; }
__device__ __forceinline__ short f2bf_rn(float f) {
    unsigned u = f_as_u(f);
    unsigned r = (u + 0x7FFFu + ((u >> 16) & 1u)) >> 16;
    return (short)r;
}
__device__ __forceinline__ float bf2f(short s) { return u_as_f(((unsigned)(unsigned short)s) << 16); }

// ---------------- degree count ----------------
__global__ __launch_bounds__(256) void k_count(const int* __restrict__ dst,
                                               unsigned* __restrict__ counts, int e) {
    int i = blockIdx.x * 256 + threadIdx.x;
    if (i < e) atomicAdd(&counts[dst[i]], 1u);
}

__global__ __launch_bounds__(256) void k_dinv(const unsigned* __restrict__ counts,
                                              float* __restrict__ dinv, int n) {
    int i = blockIdx.x * 256 + threadIdx.x;
    if (i < n) dinv[i] = rsqrtf((float)(counts[i] + 1u));  // +1 self loop
}

// ---------------- 2-level exclusive scan over counts ----------------
__global__ __launch_bounds__(256) void k_blocksum(const unsigned* __restrict__ counts,
                                                  unsigned* __restrict__ partials, int n) {
    __shared__ unsigned s[256];
    int base = blockIdx.x * 1024;
    unsigned sum = 0;
    for (int j = threadIdx.x; j < 1024; j += 256) {
        int i = base + j;
        sum += (i < n) ? counts[i] : 0u;
    }
    s[threadIdx.x] = sum;
    __syncthreads();
    for (int off = 128; off > 0; off >>= 1) {
        if (threadIdx.x < (unsigned)off) s[threadIdx.x] += s[threadIdx.x + off];
        __syncthreads();
    }
    if (threadIdx.x == 0) partials[blockIdx.x] = s[0];
}

__global__ __launch_bounds__(128) void k_scanpartials(unsigned* __restrict__ partials, int nb) {
    __shared__ unsigned s[128];
    int t = threadIdx.x;
    s[t] = (t < nb) ? partials[t] : 0u;
    __syncthreads();
    if (t == 0) {
        unsigned run = 0;
        for (int i = 0; i < nb; ++i) { unsigned v = s[i]; s[i] = run; run += v; }
    }
    __syncthreads();
    if (t < nb) partials[t] = s[t];
}

__global__ __launch_bounds__(256) void k_scanblock(const unsigned* __restrict__ counts,
                                                   const unsigned* __restrict__ partials,
                                                   unsigned* __restrict__ row_start, int n) {
    __shared__ unsigned s[256];
    int base = blockIdx.x * 1024;
    int t = threadIdx.x;
    unsigned v[4];
    unsigned tsum = 0;
#pragma unroll
    for (int j = 0; j < 4; ++j) {
        int i = base + t * 4 + j;
        v[j] = (i < n) ? counts[i] : 0u;
        tsum += v[j];
    }
    s[t] = tsum;
    __syncthreads();
    for (int off = 1; off < 256; off <<= 1) {
        unsigned x = (t >= off) ? s[t - off] : 0u;
        __syncthreads();
        s[t] += x;
        __syncthreads();
    }
    unsigned excl = (t > 0 ? s[t - 1] : 0u) + partials[blockIdx.x];
#pragma unroll
    for (int j = 0; j < 4; ++j) {
        int i = base + t * 4 + j;
        if (i < n) {
            row_start[i] = excl;
            excl += v[j];
            if (i == n - 1) row_start[n] = excl;
        }
    }
}

// ---------------- CSR fill ----------------
__global__ __launch_bounds__(256) void k_fill(const int* __restrict__ src, const int* __restrict__ dst,
                                              const unsigned* __restrict__ row_start,
                                              unsigned* __restrict__ fill,
                                              unsigned* __restrict__ col, float* __restrict__ val,
                                              const float* __restrict__ dinv, int e) {
    int i = blockIdx.x * 256 + threadIdx.x;
    if (i >= e) return;
    int d = dst[i], s0 = src[i];
    unsigned pos = row_start[d] + atomicAdd(&fill[d], 1u);
    col[pos] = (unsigned)s0;
    val[pos] = dinv[s0] * dinv[d];
}

// ---------------- embedding -> bf16 padded rows ----------------
__global__ __launch_bounds__(256) void k_embed(const int* __restrict__ x,
                                               const float* __restrict__ at,
                                               const float* __restrict__ wt,
                                               short* __restrict__ h, int n) {
    int idx = blockIdx.x * 256 + threadIdx.x;
    if (idx >= n * CH) return;
    int i = idx / CH;
    int c8 = idx - i * CH;
    int bc = c8 * 8;
    bf16x8 out;
    if (c8 >= 38) {
#pragma unroll
        for (int j = 0; j < 8; ++j) out[j] = 0;
    } else {
        int a = x[2 * i], w = x[2 * i + 1];
        float v[8];
        if (c8 < 37) {
            const float4* pa = (const float4*)&at[a * 300 + bc];
            const float4* pw = (const float4*)&wt[w * 300 + bc];
            float4 a0 = pa[0], a1 = pa[1], w0 = pw[0], w1 = pw[1];
            v[0] = a0.x + w0.x; v[1] = a0.y + w0.y; v[2] = a0.z + w0.z; v[3] = a0.w + w0.w;
            v[4] = a1.x + w1.x; v[5] = a1.y + w1.y; v[6] = a1.z + w1.z; v[7] = a1.w + w1.w;
        } else {
#pragma unroll
            for (int j = 0; j < 8; ++j) {
                int c = bc + j;
                v[j] = (c < 300) ? (at[a * 300 + c] + wt[w * 300 + c]) : 0.f;
            }
        }
#pragma unroll
        for (int j = 0; j < 8; ++j) out[j] = f2bf_rn(v[j]);
    }
    *(bf16x8*)&h[(size_t)i * PADD + bc] = out;
}

// ---------------- W pack for 32x32x16 MFMA: frag f = ((S*10+ntg)*2+hl) ----------------
// lane layout: B[k][n] with n = ntg*32 + (lane&31), k = S*16 + (lane>>5)*8 + j
__global__ __launch_bounds__(256) void k_packW(const float* __restrict__ W,
                                               short* __restrict__ Wp) {
    int t = blockIdx.x * 256 + threadIdx.x;
    if (t >= 20 * 10 * 2 * 64) return;      // 25600
    int lane = t & 63;
    int f = t >> 6;                          // 0..399
    int hl = f & 1;
    int r = f >> 1;                          // S*10 + ntg
    int S = r / 10;
    int ntg = r - S * 10;
    int n = ntg * 32 + (lane & 31);
    int kbase = S * 16 + (lane >> 5) * 8;
    bf16x8 out;
#pragma unroll
    for (int j = 0; j < 8; ++j) {
        int k = kbase + j;
        float v = (k < 300 && n < 300) ? W[k * 300 + n] : 0.f;
        short hi = f2bf_rn(v);
        out[j] = hl ? f2bf_rn(v - bf2f(hi)) : hi;
    }
    *(bf16x8*)&Wp[(size_t)t * 8] = out;
}

// ---------------- GEMM: Cb[M,320](bf16) = A[M,320](bf16) * W, 32x32x16 MFMA, hi/lo ----------------
// Block 256 thr (4 waves): BM=256 (wave: 64 rows = 2 m-frags of 32), BN=160 (5 n-frags of 32).
// grid (ceil(M/256), 2). K = 320 = 10 kt of 32 (2 MFMA k-steps each).
#define G_BM 256
#define LDS_RS 40  // LDS row stride in shorts; 16B-unit stride 5 (odd) -> conflict-free frag reads

__global__ __launch_bounds__(256, 2) void k_gemm3(const short* __restrict__ A,
                                                  const short* __restrict__ Wp,
                                                  short* __restrict__ Cb, int M) {
    __shared__ short As[G_BM * LDS_RS];
    const int tid = threadIdx.x;
    const int wave = tid >> 6;
    const int lane = tid & 63;
    const int l31 = lane & 31;
    const int lh = lane >> 5;
    const int bm0 = blockIdx.x * G_BM;
    const int bn = blockIdx.y;  // 0..1

    f32x16 acc[2][5];
#pragma unroll
    for (int mi = 0; mi < 2; ++mi)
#pragma unroll
        for (int nt = 0; nt < 5; ++nt)
#pragma unroll
            for (int q = 0; q < 16; ++q) acc[mi][nt][q] = 0.f;

    for (int kt = 0; kt < 10; ++kt) {
        const int k0 = kt * 32;
        // ---- stage A[bm0..+256][k0..+32] bf16 -> LDS ----
#pragma unroll
        for (int it = 0; it < 4; ++it) {
            int idx = it * 256 + tid;        // 0..1023
            int row = idx >> 2, c = idx & 3;
            int grow = bm0 + row;
            bf16x8 v;
            if (grow < M) {
                v = *(const bf16x8*)&A[(size_t)grow * PADD + k0 + c * 8];
            } else {
#pragma unroll
                for (int j = 0; j < 8; ++j) v[j] = 0;
            }
            *(bf16x8*)&As[row * LDS_RS + c * 8] = v;
        }
        __syncthreads();

#pragma unroll
        for (int s = 0; s < 2; ++s) {
            // B frags for this k-step (from L2-resident packed W)
            bf16x8 bf[5][2];
            int S = kt * 2 + s;
#pragma unroll
            for (int nt = 0; nt < 5; ++nt) {
                int ntg = bn * 5 + nt;
                size_t fb = ((size_t)((S * 10 + ntg) * 2) * 64 + lane) * 8;
                bf[nt][0] = *(const bf16x8*)&Wp[fb];
                bf[nt][1] = *(const bf16x8*)&Wp[fb + 64 * 8];
            }
            // A frags from LDS
            bf16x8 af[2];
#pragma unroll
            for (int mi = 0; mi < 2; ++mi)
                af[mi] = *(const bf16x8*)&As[(wave * 64 + mi * 32 + l31) * LDS_RS + s * 16 + lh * 8];
#pragma unroll
            for (int nt = 0; nt < 5; ++nt) {
#pragma unroll
                for (int mi = 0; mi < 2; ++mi) {
                    acc[mi][nt] = __builtin_amdgcn_mfma_f32_32x32x16_bf16(af[mi], bf[nt][0], acc[mi][nt], 0, 0, 0);
                    acc[mi][nt] = __builtin_amdgcn_mfma_f32_32x32x16_bf16(af[mi], bf[nt][1], acc[mi][nt], 0, 0, 0);
                }
            }
        }
        __syncthreads();
    }

    // ---- epilogue: C/D col=lane&31, row=(reg&3)+8*(reg>>2)+4*(lane>>5) ----
#pragma unroll
    for (int mi = 0; mi < 2; ++mi) {
#pragma unroll
        for (int nt = 0; nt < 5; ++nt) {
            int colg = bn * 160 + nt * 32 + l31;   // pad cols hold zeros (W pad = 0)
            int row0 = bm0 + wave * 64 + mi * 32 + 4 * lh;
#pragma unroll
            for (int reg = 0; reg < 16; ++reg) {
                int row = row0 + (reg & 3) + 8 * (reg >> 2);
                if (row < M) Cb[(size_t)row * PADD + colg] = f2bf_rn(acc[mi][nt][reg]);
            }
        }
    }
}

// ---------------- aggregation: h = bf16( b + D^-1/2 A D^-1/2 hw ) ----------------
__global__ __launch_bounds__(256) void k_agg(const short* __restrict__ hw,
                                             const float* __restrict__ dinv,
                                             const unsigned* __restrict__ row_start,
                                             const unsigned* __restrict__ col,
                                             const float* __restrict__ val,
                                             const float* __restrict__ b,
                                             short* __restrict__ hout, int n) {
    int idx = blockIdx.x * 256 + threadIdx.x;
    if (idx >= n * CH) return;
    int i = idx / CH;
    int c8 = idx - i * CH;
    int bc = c8 * 8;

    float acc[8];
    if (c8 < 37) {
        const float4* pb = (const float4*)&b[bc];
        float4 b0 = pb[0], b1 = pb[1];
        acc[0] = b0.x; acc[1] = b0.y; acc[2] = b0.z; acc[3] = b0.w;
        acc[4] = b1.x; acc[5] = b1.y; acc[6] = b1.z; acc[7] = b1.w;
    } else {
#pragma unroll
        for (int j = 0; j < 8; ++j) {
            int c = bc + j;
            acc[j] = (c < 300) ? b[c] : 0.f;
        }
    }

    float di = dinv[i];
    float sn = di * di;
    bf16x8 sv = *(const bf16x8*)&hw[(size_t)i * PADD + bc];
#pragma unroll
    for (int j = 0; j < 8; ++j) acc[j] += sn * bf2f(sv[j]);

    unsigned e0 = row_start[i], e1 = row_start[i + 1];
    unsigned e = e0;
    for (; e + 2 <= e1; e += 2) {
        unsigned c0 = col[e], c1 = col[e + 1];
        float v0 = val[e], v1 = val[e + 1];
        bf16x8 m0 = *(const bf16x8*)&hw[(size_t)c0 * PADD + bc];
        bf16x8 m1 = *(const bf16x8*)&hw[(size_t)c1 * PADD + bc];
#pragma unroll
        for (int j = 0; j < 8; ++j) acc[j] += v0 * bf2f(m0[j]) + v1 * bf2f(m1[j]);
    }
    if (e < e1) {
        unsigned c0 = col[e];
        float v0 = val[e];
        bf16x8 m0 = *(const bf16x8*)&hw[(size_t)c0 * PADD + bc];
#pragma unroll
        for (int j = 0; j < 8; ++j) acc[j] += v0 * bf2f(m0[j]);
    }

    bf16x8 out;
#pragma unroll
    for (int j = 0; j < 8; ++j) out[j] = f2bf_rn(acc[j]);
    *(bf16x8*)&hout[(size_t)i * PADD + bc] = out;
}

// ---------------- graph boundaries (batch sorted) ----------------
__global__ __launch_bounds__(128) void k_gstart(const int* __restrict__ batch,
                                                int* __restrict__ gstart, int n, int ngraph) {
    int g = threadIdx.x;
    if (g > ngraph) return;
    if (g == ngraph) { gstart[g] = n; return; }
    int lo = 0, hi = n;
    while (lo < hi) {
        int mid = (lo + hi) >> 1;
        if (batch[mid] < g) lo = mid + 1; else hi = mid;
    }
    gstart[g] = lo;
}

// ---------------- pool: 64 graphs x 16 chunks, vectorized row-major reads ----------------
__global__ __launch_bounds__(256) void k_pool(const short* __restrict__ h,
                                              const int* __restrict__ gstart,
                                              float* __restrict__ psum) {
    __shared__ float red[6][40][8];
    int g = blockIdx.x >> 4;
    int chunk = blockIdx.x & 15;
    int lo = gstart[g], hi = gstart[g + 1];
    int cnt = hi - lo;
    int s = lo + (int)((long)cnt * chunk / 16);
    int e2 = lo + (int)((long)cnt * (chunk + 1) / 16);
    int t = threadIdx.x;
    int c8 = t % 40;
    int rl = t / 40;                 // 0..6 (rl==6 lanes inactive)
    bool live = (rl < 6) && (c8 < 38);

    float acc[8];
#pragma unroll
    for (int j = 0; j < 8; ++j) acc[j] = 0.f;

    if (live) {
        int r = s + rl;
        for (; r + 6 < e2; r += 12) {
            bf16x8 v0 = *(const bf16x8*)&h[(size_t)r * PADD + c8 * 8];
            bf16x8 v1 = *(const bf16x8*)&h[(size_t)(r + 6) * PADD + c8 * 8];
#pragma unroll
            for (int j = 0; j < 8; ++j) acc[j] += bf2f(v0[j]) + bf2f(v1[j]);
        }
        if (r < e2) {
            bf16x8 v0 = *(const bf16x8*)&h[(size_t)r * PADD + c8 * 8];
#pragma unroll
            for (int j = 0; j < 8; ++j) acc[j] += bf2f(v0[j]);
        }
    }
    if (rl < 6) {
#pragma unroll
        for (int j = 0; j < 8; ++j) red[rl][c8][j] = acc[j];
    }
    __syncthreads();
    if (t < 38) {
        float s8[8];
#pragma unroll
        for (int j = 0; j < 8; ++j)
            s8[j] = red[0][t][j] + red[1][t][j] + red[2][t][j] +
                    red[3][t][j] + red[4][t][j] + red[5][t][j];
#pragma unroll
        for (int j = 0; j < 8; ++j) {
            int c = t * 8 + j;
            if (c < 300) atomicAdd(&psum[g * 300 + c], s8[j]);
        }
    }
}

__global__ __launch_bounds__(256) void k_div(const float* __restrict__ psum,
                                             const int* __restrict__ gstart,
                                             float* __restrict__ out) {
    int j = blockIdx.x * 256 + threadIdx.x;
    if (j >= NGRAPH_C * 300) return;
    int g = j / 300;
    int c2 = gstart[g + 1] - gstart[g];
    out[j] = psum[j] / (float)(c2 > 0 ? c2 : 1);
}

// ---------------- launch ----------------
extern "C" void kernel_launch(void* const* d_in, const int* in_sizes, int n_in,
                              void* d_out, int out_size, void* d_ws, size_t ws_size,
                              hipStream_t stream) {
    const int*   x     = (const int*)d_in[0];
    const int*   ei    = (const int*)d_in[1];
    const int*   batch = (const int*)d_in[2];
    const float* at    = (const float*)d_in[3];
    const float* wt    = (const float*)d_in[4];
    const float* W     = (const float*)d_in[5];
    const float* b     = (const float*)d_in[6];

    const int n = in_sizes[0] / 2;   // 100000
    const int e = in_sizes[1] / 2;   // 800000

    char* ws = (char*)d_ws;
    size_t off = 0;
    auto carve = [&](size_t bytes) {
        void* p = ws + off;
        off += (bytes + 255) & ~(size_t)255;
        return p;
    };
    short*    h         = (short*)carve((size_t)n * PADD * 2);
    short*    hw        = (short*)carve((size_t)n * PADD * 2);
    float*    dinv      = (float*)carve((size_t)n * 4);
    unsigned* counts    = (unsigned*)carve((size_t)n * 4);
    unsigned* fill      = (unsigned*)carve((size_t)n * 4);
    unsigned* row_start = (unsigned*)carve((size_t)(n + 1) * 4);
    unsigned* partials  = (unsigned*)carve(1024 * 4);
    unsigned* colb      = (unsigned*)carve((size_t)e * 4);
    float*    val       = (float*)carve((size_t)e * 4);
    int*      gstart    = (int*)carve(65 * 4);
    float*    psum      = (float*)carve((size_t)NGRAPH_C * 300 * 4);
    short*    Wp        = (short*)carve((size_t)20 * 10 * 2 * 64 * 8 * 2);

    const int* src = ei;
    const int* dst = ei + e;

    hipMemsetAsync(counts, 0, (size_t)n * 4, stream);
    hipMemsetAsync(fill, 0, (size_t)n * 4, stream);
    hipMemsetAsync(psum, 0, (size_t)NGRAPH_C * 300 * 4, stream);

    int eb = (e + 255) / 256;
    int nb256 = (n + 255) / 256;
    int NB = (n + 1023) / 1024;  // 98

    k_count<<<eb, 256, 0, stream>>>(dst, counts, e);
    k_dinv<<<nb256, 256, 0, stream>>>(counts, dinv, n);
    k_blocksum<<<NB, 256, 0, stream>>>(counts, partials, n);
    k_scanpartials<<<1, 128, 0, stream>>>(partials, NB);
    k_scanblock<<<NB, 256, 0, stream>>>(counts, partials, row_start, n);
    k_fill<<<eb, 256, 0, stream>>>(src, dst, row_start, fill, colb, val, dinv, e);
    k_gstart<<<1, 128, 0, stream>>>(batch, gstart, n, NGRAPH_C);
    k_packW<<<(20 * 10 * 2 * 64 + 255) / 256, 256, 0, stream>>>(W, Wp);

    int gb = (n * CH + 255) / 256;
    k_embed<<<gb, 256, 0, stream>>>(x, at, wt, h, n);

    dim3 ggrid((n + G_BM - 1) / G_BM, 2);
    for (int hop = 0; hop < 3; ++hop) {
        k_gemm3<<<ggrid, 256, 0, stream>>>(h, Wp, hw, n);
        k_agg<<<gb, 256, 0, stream>>>(hw, dinv, row_start, colb, val, b, h, n);
    }

    k_pool<<<NGRAPH_C * 16, 256, 0, stream>>>(h, gstart, psum);
    k_div<<<(NGRAPH_C * 300 + 255) / 256, 256, 0, stream>>>(psum, gstart, (float*)d_out);
}

// Round 6
// 661.022 us; speedup vs baseline: 4.6649x; 1.1440x over previous
//
#include <hip/hip_runtime.h>
#include <hip/hip_bf16.h>

#define N_NODES_C 100000
#define N_EDGES_C 800000
#define DIM_C 300
#define PADD 320          // padded feature dim (10 k-tiles of 32)
#define CH 40             // 16B bf16x8 chunks per row (320/8)
#define NGRAPH_C 64

typedef short bf16x8 __attribute__((ext_vector_type(8)));
typedef float f32x4 __attribute__((ext_vector_type(4)));

// ---- bf16 helpers (manual RN-even) ----
__device__ __forceinline__ unsigned f_as_u(float f) { union { float f; unsigned u; } c; c.f = f; return c.u; }
__device__ __forceinline__ float u_as_f(unsigned u) { union { unsigned u; float f; } c; c.u = u; return c.f; }
__device__ __forceinline__ short f2bf_rn(float f) {
    unsigned u = f_as_u(f);
    unsigned r = (u + 0x7FFFu + ((u >> 16) & 1u)) >> 16;
    return (short)r;
}
__device__ __forceinline__ float bf2f(short s) { return u_as_f(((unsigned)(unsigned short)s) << 16); }

// ---------------- degree count ----------------
__global__ __launch_bounds__(256) void k_count(const int* __restrict__ dst,
                                               unsigned* __restrict__ counts, int e) {
    int i = blockIdx.x * 256 + threadIdx.x;
    if (i < e) atomicAdd(&counts[dst[i]], 1u);
}

__global__ __launch_bounds__(256) void k_dinv(const unsigned* __restrict__ counts,
                                              float* __restrict__ dinv, int n) {
    int i = blockIdx.x * 256 + threadIdx.x;
    if (i < n) dinv[i] = rsqrtf((float)(counts[i] + 1u));  // +1 self loop
}

// ---------------- 2-level exclusive scan over counts ----------------
__global__ __launch_bounds__(256) void k_blocksum(const unsigned* __restrict__ counts,
                                                  unsigned* __restrict__ partials, int n) {
    __shared__ unsigned s[256];
    int base = blockIdx.x * 1024;
    unsigned sum = 0;
    for (int j = threadIdx.x; j < 1024; j += 256) {
        int i = base + j;
        sum += (i < n) ? counts[i] : 0u;
    }
    s[threadIdx.x] = sum;
    __syncthreads();
    for (int off = 128; off > 0; off >>= 1) {
        if (threadIdx.x < (unsigned)off) s[threadIdx.x] += s[threadIdx.x + off];
        __syncthreads();
    }
    if (threadIdx.x == 0) partials[blockIdx.x] = s[0];
}

__global__ __launch_bounds__(128) void k_scanpartials(unsigned* __restrict__ partials, int nb) {
    __shared__ unsigned s[128];
    int t = threadIdx.x;
    s[t] = (t < nb) ? partials[t] : 0u;
    __syncthreads();
    if (t == 0) {
        unsigned run = 0;
        for (int i = 0; i < nb; ++i) { unsigned v = s[i]; s[i] = run; run += v; }
    }
    __syncthreads();
    if (t < nb) partials[t] = s[t];
}

__global__ __launch_bounds__(256) void k_scanblock(const unsigned* __restrict__ counts,
                                                   const unsigned* __restrict__ partials,
                                                   unsigned* __restrict__ row_start, int n) {
    __shared__ unsigned s[256];
    int base = blockIdx.x * 1024;
    int t = threadIdx.x;
    unsigned v[4];
    unsigned tsum = 0;
#pragma unroll
    for (int j = 0; j < 4; ++j) {
        int i = base + t * 4 + j;
        v[j] = (i < n) ? counts[i] : 0u;
        tsum += v[j];
    }
    s[t] = tsum;
    __syncthreads();
    for (int off = 1; off < 256; off <<= 1) {
        unsigned x = (t >= off) ? s[t - off] : 0u;
        __syncthreads();
        s[t] += x;
        __syncthreads();
    }
    unsigned excl = (t > 0 ? s[t - 1] : 0u) + partials[blockIdx.x];
#pragma unroll
    for (int j = 0; j < 4; ++j) {
        int i = base + t * 4 + j;
        if (i < n) {
            row_start[i] = excl;
            excl += v[j];
            if (i == n - 1) row_start[n] = excl;
        }
    }
}

// ---------------- CSR fill ----------------
__global__ __launch_bounds__(256) void k_fill(const int* __restrict__ src, const int* __restrict__ dst,
                                              const unsigned* __restrict__ row_start,
                                              unsigned* __restrict__ fill,
                                              unsigned* __restrict__ col, float* __restrict__ val,
                                              const float* __restrict__ dinv, int e) {
    int i = blockIdx.x * 256 + threadIdx.x;
    if (i >= e) return;
    int d = dst[i], s0 = src[i];
    unsigned pos = row_start[d] + atomicAdd(&fill[d], 1u);
    col[pos] = (unsigned)s0;
    val[pos] = dinv[s0] * dinv[d];
}

// ---------------- embedding -> bf16 padded rows ----------------
__global__ __launch_bounds__(256) void k_embed(const int* __restrict__ x,
                                               const float* __restrict__ at,
                                               const float* __restrict__ wt,
                                               short* __restrict__ h, int n) {
    int idx = blockIdx.x * 256 + threadIdx.x;
    if (idx >= n * CH) return;
    int i = idx / CH;
    int c8 = idx - i * CH;
    int bc = c8 * 8;
    bf16x8 out;
    if (c8 >= 38) {
#pragma unroll
        for (int j = 0; j < 8; ++j) out[j] = 0;
    } else {
        int a = x[2 * i], w = x[2 * i + 1];
        float v[8];
        if (c8 < 37) {
            const float4* pa = (const float4*)&at[a * 300 + bc];
            const float4* pw = (const float4*)&wt[w * 300 + bc];
            float4 a0 = pa[0], a1 = pa[1], w0 = pw[0], w1 = pw[1];
            v[0] = a0.x + w0.x; v[1] = a0.y + w0.y; v[2] = a0.z + w0.z; v[3] = a0.w + w0.w;
            v[4] = a1.x + w1.x; v[5] = a1.y + w1.y; v[6] = a1.z + w1.z; v[7] = a1.w + w1.w;
        } else {
#pragma unroll
            for (int j = 0; j < 8; ++j) {
                int c = bc + j;
                v[j] = (c < 300) ? (at[a * 300 + c] + wt[w * 300 + c]) : 0.f;
            }
        }
#pragma unroll
        for (int j = 0; j < 8; ++j) out[j] = f2bf_rn(v[j]);
    }
    *(bf16x8*)&h[(size_t)i * PADD + bc] = out;
}

// ---------------- W pack: Wp[(kt*2+hl)*320 + n][k] (k=0..31 within kt), hi/lo ----------------
// 16B unit u = t: k8=u&3, n=(u>>2)%320, khl=(u>>2)/320 -> kt=khl>>1, hl=khl&1
__global__ __launch_bounds__(256) void k_packW(const float* __restrict__ W,
                                               short* __restrict__ Wp) {
    int t = blockIdx.x * 256 + threadIdx.x;
    if (t >= 25600) return;
    int k8 = t & 3;
    int n = (t >> 2) % 320;
    int khl = (t >> 2) / 320;
    int kt = khl >> 1, hl = khl & 1;
    bf16x8 out;
#pragma unroll
    for (int j = 0; j < 8; ++j) {
        int gk = kt * 32 + k8 * 8 + j;
        float v = (gk < 300 && n < 300) ? W[gk * 300 + n] : 0.f;
        short hi = f2bf_rn(v);
        out[j] = hl ? f2bf_rn(v - bf2f(hi)) : hi;
    }
    *(bf16x8*)&Wp[(size_t)t * 8] = out;
}

// ---------------- GEMM: Cb[M,320](bf16) = A[M,320](bf16) * W, 16x16x32 MFMA, hi/lo ----------------
// Block 256 thr = 4 waves in 2x2: wave tile 64 rows x 80 cols (4 m-frags x 5 n-frags).
// BM=128, BN=160, grid (ceil(M/128), 2). B staged to LDS once per block per kt.
#define G_BM 128

__global__ __launch_bounds__(256, 2) void k_gemm4(const short* __restrict__ A,
                                                  const short* __restrict__ Wp,
                                                  short* __restrict__ Cb, int M) {
    __shared__ short As[128 * 32];        // [row][k], k-contiguous, 8 KB
    __shared__ short Bs[2 * 160 * 32];    // [hl][n][k], k-contiguous, 20 KB
    const int tid = threadIdx.x;
    const int wave = tid >> 6;
    const int lane = tid & 63;
    const int r15 = lane & 15;
    const int q = lane >> 4;
    const int wm = wave >> 1;             // 0..1 (row half)
    const int wn = wave & 1;              // 0..1 (col half)
    const int bm0 = blockIdx.x * G_BM;
    const int bn = blockIdx.y;            // 0..1

    f32x4 acc[4][5];
#pragma unroll
    for (int mi = 0; mi < 4; ++mi)
#pragma unroll
        for (int nt = 0; nt < 5; ++nt) acc[mi][nt] = (f32x4){0.f, 0.f, 0.f, 0.f};

    for (int kt = 0; kt < 10; ++kt) {
        // ---- stage A[bm0..+128][kt*32..+32] -> As (conflict-free, coalesced) ----
#pragma unroll
        for (int rr = 0; rr < 2; ++rr) {
            int u = rr * 256 + tid;        // 0..511
            int row = u >> 2, k8 = u & 3;
            int grow = bm0 + row;
            bf16x8 v;
            if (grow < M) {
                v = *(const bf16x8*)&A[(size_t)grow * PADD + kt * 32 + k8 * 8];
            } else {
#pragma unroll
                for (int j = 0; j < 8; ++j) v[j] = 0;
            }
            *(bf16x8*)&As[row * 32 + k8 * 8] = v;
        }
        // ---- stage B (hi+lo, 160 cols of this bn) -> Bs ----
#pragma unroll
        for (int rr = 0; rr < 5; ++rr) {
            int u = rr * 256 + tid;        // 0..1279
            int hl = u / 640;
            int rem = u - hl * 640;        // n_loc*4 + k8
            bf16x8 v = *(const bf16x8*)&Wp[((size_t)(kt * 2 + hl) * 1280 + (size_t)bn * 640 + rem) * 8];
            *(bf16x8*)&Bs[hl * 5120 + rem * 8] = v;
        }
        __syncthreads();

        // ---- fragments ----
        bf16x8 af[4];
#pragma unroll
        for (int mi = 0; mi < 4; ++mi)
            af[mi] = *(const bf16x8*)&As[(wm * 64 + mi * 16 + r15) * 32 + q * 8];
        bf16x8 bfh[5], bfl[5];
#pragma unroll
        for (int nt = 0; nt < 5; ++nt) {
            int nl = wn * 80 + nt * 16 + r15;
            bfh[nt] = *(const bf16x8*)&Bs[nl * 32 + q * 8];
            bfl[nt] = *(const bf16x8*)&Bs[5120 + nl * 32 + q * 8];
        }
#pragma unroll
        for (int nt = 0; nt < 5; ++nt) {
#pragma unroll
            for (int mi = 0; mi < 4; ++mi) {
                acc[mi][nt] = __builtin_amdgcn_mfma_f32_16x16x32_bf16(af[mi], bfh[nt], acc[mi][nt], 0, 0, 0);
                acc[mi][nt] = __builtin_amdgcn_mfma_f32_16x16x32_bf16(af[mi], bfl[nt], acc[mi][nt], 0, 0, 0);
            }
        }
        __syncthreads();
    }

    // ---- epilogue: C/D col=lane&15, row=quad*4+reg ----
#pragma unroll
    for (int mi = 0; mi < 4; ++mi) {
#pragma unroll
        for (int nt = 0; nt < 5; ++nt) {
            int col = bn * 160 + wn * 80 + nt * 16 + r15;  // pad cols hold zeros (W pad = 0)
            int row0 = bm0 + wm * 64 + mi * 16 + q * 4;
            f32x4 c = acc[mi][nt];
#pragma unroll
            for (int reg = 0; reg < 4; ++reg) {
                int row = row0 + reg;
                if (row < M) Cb[(size_t)row * PADD + col] = f2bf_rn(c[reg]);
            }
        }
    }
}

// ---------------- aggregation: h = bf16( b + D^-1/2 A D^-1/2 hw ) ----------------
__global__ __launch_bounds__(256) void k_agg(const short* __restrict__ hw,
                                             const float* __restrict__ dinv,
                                             const unsigned* __restrict__ row_start,
                                             const unsigned* __restrict__ col,
                                             const float* __restrict__ val,
                                             const float* __restrict__ b,
                                             short* __restrict__ hout, int n) {
    int idx = blockIdx.x * 256 + threadIdx.x;
    if (idx >= n * CH) return;
    int i = idx / CH;
    int c8 = idx - i * CH;
    int bc = c8 * 8;

    float acc[8];
    if (c8 < 37) {
        const float4* pb = (const float4*)&b[bc];
        float4 b0 = pb[0], b1 = pb[1];
        acc[0] = b0.x; acc[1] = b0.y; acc[2] = b0.z; acc[3] = b0.w;
        acc[4] = b1.x; acc[5] = b1.y; acc[6] = b1.z; acc[7] = b1.w;
    } else {
#pragma unroll
        for (int j = 0; j < 8; ++j) {
            int c = bc + j;
            acc[j] = (c < 300) ? b[c] : 0.f;
        }
    }

    float di = dinv[i];
    float sn = di * di;
    bf16x8 sv = *(const bf16x8*)&hw[(size_t)i * PADD + bc];
#pragma unroll
    for (int j = 0; j < 8; ++j) acc[j] += sn * bf2f(sv[j]);

    unsigned e0 = row_start[i], e1 = row_start[i + 1];
    unsigned e = e0;
    for (; e + 2 <= e1; e += 2) {
        unsigned c0 = col[e], c1 = col[e + 1];
        float v0 = val[e], v1 = val[e + 1];
        bf16x8 m0 = *(const bf16x8*)&hw[(size_t)c0 * PADD + bc];
        bf16x8 m1 = *(const bf16x8*)&hw[(size_t)c1 * PADD + bc];
#pragma unroll
        for (int j = 0; j < 8; ++j) acc[j] += v0 * bf2f(m0[j]) + v1 * bf2f(m1[j]);
    }
    if (e < e1) {
        unsigned c0 = col[e];
        float v0 = val[e];
        bf16x8 m0 = *(const bf16x8*)&hw[(size_t)c0 * PADD + bc];
#pragma unroll
        for (int j = 0; j < 8; ++j) acc[j] += v0 * bf2f(m0[j]);
    }

    bf16x8 out;
#pragma unroll
    for (int j = 0; j < 8; ++j) out[j] = f2bf_rn(acc[j]);
    *(bf16x8*)&hout[(size_t)i * PADD + bc] = out;
}

// ---------------- graph boundaries (batch sorted) ----------------
__global__ __launch_bounds__(128) void k_gstart(const int* __restrict__ batch,
                                                int* __restrict__ gstart, int n, int ngraph) {
    int g = threadIdx.x;
    if (g > ngraph) return;
    if (g == ngraph) { gstart[g] = n; return; }
    int lo = 0, hi = n;
    while (lo < hi) {
        int mid = (lo + hi) >> 1;
        if (batch[mid] < g) lo = mid + 1; else hi = mid;
    }
    gstart[g] = lo;
}

// ---------------- pool: 64 graphs x 16 chunks, vectorized row-major reads ----------------
__global__ __launch_bounds__(256) void k_pool(const short* __restrict__ h,
                                              const int* __restrict__ gstart,
                                              float* __restrict__ psum) {
    __shared__ float red[6][40][8];
    int g = blockIdx.x >> 4;
    int chunk = blockIdx.x & 15;
    int lo = gstart[g], hi = gstart[g + 1];
    int cnt = hi - lo;
    int s = lo + (int)((long)cnt * chunk / 16);
    int e2 = lo + (int)((long)cnt * (chunk + 1) / 16);
    int t = threadIdx.x;
    int c8 = t % 40;
    int rl = t / 40;                 // 0..6 (rl==6 lanes inactive)
    bool live = (rl < 6) && (c8 < 38);

    float acc[8];
#pragma unroll
    for (int j = 0; j < 8; ++j) acc[j] = 0.f;

    if (live) {
        int r = s + rl;
        for (; r + 6 < e2; r += 12) {
            bf16x8 v0 = *(const bf16x8*)&h[(size_t)r * PADD + c8 * 8];
            bf16x8 v1 = *(const bf16x8*)&h[(size_t)(r + 6) * PADD + c8 * 8];
#pragma unroll
            for (int j = 0; j < 8; ++j) acc[j] += bf2f(v0[j]) + bf2f(v1[j]);
        }
        if (r < e2) {
            bf16x8 v0 = *(const bf16x8*)&h[(size_t)r * PADD + c8 * 8];
#pragma unroll
            for (int j = 0; j < 8; ++j) acc[j] += bf2f(v0[j]);
        }
    }
    if (rl < 6) {
#pragma unroll
        for (int j = 0; j < 8; ++j) red[rl][c8][j] = acc[j];
    }
    __syncthreads();
    if (t < 38) {
        float s8[8];
#pragma unroll
        for (int j = 0; j < 8; ++j)
            s8[j] = red[0][t][j] + red[1][t][j] + red[2][t][j] +
                    red[3][t][j] + red[4][t][j] + red[5][t][j];
#pragma unroll
        for (int j = 0; j < 8; ++j) {
            int c = t * 8 + j;
            if (c < 300) atomicAdd(&psum[g * 300 + c], s8[j]);
        }
    }
}

__global__ __launch_bounds__(256) void k_div(const float* __restrict__ psum,
                                             const int* __restrict__ gstart,
                                             float* __restrict__ out) {
    int j = blockIdx.x * 256 + threadIdx.x;
    if (j >= NGRAPH_C * 300) return;
    int g = j / 300;
    int c2 = gstart[g + 1] - gstart[g];
    out[j] = psum[j] / (float)(c2 > 0 ? c2 : 1);
}

// ---------------- launch ----------------
extern "C" void kernel_launch(void* const* d_in, const int* in_sizes, int n_in,
                              void* d_out, int out_size, void* d_ws, size_t ws_size,
                              hipStream_t stream) {
    const int*   x     = (const int*)d_in[0];
    const int*   ei    = (const int*)d_in[1];
    const int*   batch = (const int*)d_in[2];
    const float* at    = (const float*)d_in[3];
    const float* wt    = (const float*)d_in[4];
    const float* W     = (const float*)d_in[5];
    const float* b     = (const float*)d_in[6];

    const int n = in_sizes[0] / 2;   // 100000
    const int e = in_sizes[1] / 2;   // 800000

    char* ws = (char*)d_ws;
    size_t off = 0;
    auto carve = [&](size_t bytes) {
        void* p = ws + off;
        off += (bytes + 255) & ~(size_t)255;
        return p;
    };
    short*    h         = (short*)carve((size_t)n * PADD * 2);
    short*    hw        = (short*)carve((size_t)n * PADD * 2);
    float*    dinv      = (float*)carve((size_t)n * 4);
    unsigned* counts    = (unsigned*)carve((size_t)n * 4);
    unsigned* fill      = (unsigned*)carve((size_t)n * 4);
    unsigned* row_start = (unsigned*)carve((size_t)(n + 1) * 4);
    unsigned* partials  = (unsigned*)carve(1024 * 4);
    unsigned* colb      = (unsigned*)carve((size_t)e * 4);
    float*    val       = (float*)carve((size_t)e * 4);
    int*      gstart    = (int*)carve(65 * 4);
    float*    psum      = (float*)carve((size_t)NGRAPH_C * 300 * 4);
    short*    Wp        = (short*)carve((size_t)25600 * 8 * 2);

    const int* src = ei;
    const int* dst = ei + e;

    hipMemsetAsync(counts, 0, (size_t)n * 4, stream);
    hipMemsetAsync(fill, 0, (size_t)n * 4, stream);
    hipMemsetAsync(psum, 0, (size_t)NGRAPH_C * 300 * 4, stream);

    int eb = (e + 255) / 256;
    int nb256 = (n + 255) / 256;
    int NB = (n + 1023) / 1024;  // 98

    k_count<<<eb, 256, 0, stream>>>(dst, counts, e);
    k_dinv<<<nb256, 256, 0, stream>>>(counts, dinv, n);
    k_blocksum<<<NB, 256, 0, stream>>>(counts, partials, n);
    k_scanpartials<<<1, 128, 0, stream>>>(partials, NB);
    k_scanblock<<<NB, 256, 0, stream>>>(counts, partials, row_start, n);
    k_fill<<<eb, 256, 0, stream>>>(src, dst, row_start, fill, colb, val, dinv, e);
    k_gstart<<<1, 128, 0, stream>>>(batch, gstart, n, NGRAPH_C);
    k_packW<<<(25600 + 255) / 256, 256, 0, stream>>>(W, Wp);

    int gb = (n * CH + 255) / 256;
    k_embed<<<gb, 256, 0, stream>>>(x, at, wt, h, n);

    dim3 ggrid((n + G_BM - 1) / G_BM, 2);
    for (int hop = 0; hop < 3; ++hop) {
        k_gemm4<<<ggrid, 256, 0, stream>>>(h, Wp, hw, n);
        k_agg<<<gb, 256, 0, stream>>>(hw, dinv, row_start, colb, val, b, h, n);
    }

    k_pool<<<NGRAPH_C * 16, 256, 0, stream>>>(h, gstart, psum);
    k_div<<<(NGRAPH_C * 300 + 255) / 256, 256, 0, stream>>>(psum, gstart, (float*)d_out);
}

// Round 7
// 637.312 us; speedup vs baseline: 4.8384x; 1.0372x over previous
//
#include <hip/hip_runtime.h>
#include <hip/hip_bf16.h>

#define N_NODES_C 100000
#define N_EDGES_C 800000
#define DIM_C 300
#define PADD 320          // padded feature dim (10 k-tiles of 32)
#define CH 40             // 16B bf16x8 chunks per row (320/8)
#define CH2 20            // 32B chunks per row
#define NGRAPH_C 64

typedef short bf16x8 __attribute__((ext_vector_type(8)));
typedef float f32x4 __attribute__((ext_vector_type(4)));

// ---- bf16 helpers (manual RN-even) ----
__device__ __forceinline__ unsigned f_as_u(float f) { union { float f; unsigned u; } c; c.f = f; return c.u; }
__device__ __forceinline__ float u_as_f(unsigned u) { union { unsigned u; float f; } c; c.u = u; return c.f; }
__device__ __forceinline__ short f2bf_rn(float f) {
    unsigned u = f_as_u(f);
    unsigned r = (u + 0x7FFFu + ((u >> 16) & 1u)) >> 16;
    return (short)r;
}
__device__ __forceinline__ float bf2f(short s) { return u_as_f(((unsigned)(unsigned short)s) << 16); }

// ---------------- degree count ----------------
__global__ __launch_bounds__(256) void k_count(const int* __restrict__ dst,
                                               unsigned* __restrict__ counts, int e) {
    int i = blockIdx.x * 256 + threadIdx.x;
    if (i < e) atomicAdd(&counts[dst[i]], 1u);
}

__global__ __launch_bounds__(256) void k_dinv(const unsigned* __restrict__ counts,
                                              float* __restrict__ dinv, int n) {
    int i = blockIdx.x * 256 + threadIdx.x;
    if (i < n) dinv[i] = rsqrtf((float)(counts[i] + 1u));  // +1 self loop
}

// ---------------- 2-level exclusive scan over counts ----------------
__global__ __launch_bounds__(256) void k_blocksum(const unsigned* __restrict__ counts,
                                                  unsigned* __restrict__ partials, int n) {
    __shared__ unsigned s[256];
    int base = blockIdx.x * 1024;
    unsigned sum = 0;
    for (int j = threadIdx.x; j < 1024; j += 256) {
        int i = base + j;
        sum += (i < n) ? counts[i] : 0u;
    }
    s[threadIdx.x] = sum;
    __syncthreads();
    for (int off = 128; off > 0; off >>= 1) {
        if (threadIdx.x < (unsigned)off) s[threadIdx.x] += s[threadIdx.x + off];
        __syncthreads();
    }
    if (threadIdx.x == 0) partials[blockIdx.x] = s[0];
}

__global__ __launch_bounds__(128) void k_scanpartials(unsigned* __restrict__ partials, int nb) {
    __shared__ unsigned s[128];
    int t = threadIdx.x;
    s[t] = (t < nb) ? partials[t] : 0u;
    __syncthreads();
    if (t == 0) {
        unsigned run = 0;
        for (int i = 0; i < nb; ++i) { unsigned v = s[i]; s[i] = run; run += v; }
    }
    __syncthreads();
    if (t < nb) partials[t] = s[t];
}

__global__ __launch_bounds__(256) void k_scanblock(const unsigned* __restrict__ counts,
                                                   const unsigned* __restrict__ partials,
                                                   unsigned* __restrict__ row_start, int n) {
    __shared__ unsigned s[256];
    int base = blockIdx.x * 1024;
    int t = threadIdx.x;
    unsigned v[4];
    unsigned tsum = 0;
#pragma unroll
    for (int j = 0; j < 4; ++j) {
        int i = base + t * 4 + j;
        v[j] = (i < n) ? counts[i] : 0u;
        tsum += v[j];
    }
    s[t] = tsum;
    __syncthreads();
    for (int off = 1; off < 256; off <<= 1) {
        unsigned x = (t >= off) ? s[t - off] : 0u;
        __syncthreads();
        s[t] += x;
        __syncthreads();
    }
    unsigned excl = (t > 0 ? s[t - 1] : 0u) + partials[blockIdx.x];
#pragma unroll
    for (int j = 0; j < 4; ++j) {
        int i = base + t * 4 + j;
        if (i < n) {
            row_start[i] = excl;
            excl += v[j];
            if (i == n - 1) row_start[n] = excl;
        }
    }
}

// ---------------- CSR fill: combined (col, val) uint2 ----------------
__global__ __launch_bounds__(256) void k_fill(const int* __restrict__ src, const int* __restrict__ dst,
                                              const unsigned* __restrict__ row_start,
                                              unsigned* __restrict__ fill,
                                              uint2* __restrict__ edges,
                                              const float* __restrict__ dinv, int e) {
    int i = blockIdx.x * 256 + threadIdx.x;
    if (i >= e) return;
    int d = dst[i], s0 = src[i];
    unsigned pos = row_start[d] + atomicAdd(&fill[d], 1u);
    uint2 p;
    p.x = (unsigned)s0;
    p.y = f_as_u(dinv[s0] * dinv[d]);
    edges[pos] = p;
}

// ---------------- embedding -> bf16 padded rows ----------------
__global__ __launch_bounds__(256) void k_embed(const int* __restrict__ x,
                                               const float* __restrict__ at,
                                               const float* __restrict__ wt,
                                               short* __restrict__ h, int n) {
    int idx = blockIdx.x * 256 + threadIdx.x;
    if (idx >= n * CH) return;
    int i = idx / CH;
    int c8 = idx - i * CH;
    int bc = c8 * 8;
    bf16x8 out;
    if (c8 >= 38) {
#pragma unroll
        for (int j = 0; j < 8; ++j) out[j] = 0;
    } else {
        int a = x[2 * i], w = x[2 * i + 1];
        float v[8];
        if (c8 < 37) {
            const float4* pa = (const float4*)&at[a * 300 + bc];
            const float4* pw = (const float4*)&wt[w * 300 + bc];
            float4 a0 = pa[0], a1 = pa[1], w0 = pw[0], w1 = pw[1];
            v[0] = a0.x + w0.x; v[1] = a0.y + w0.y; v[2] = a0.z + w0.z; v[3] = a0.w + w0.w;
            v[4] = a1.x + w1.x; v[5] = a1.y + w1.y; v[6] = a1.z + w1.z; v[7] = a1.w + w1.w;
        } else {
#pragma unroll
            for (int j = 0; j < 8; ++j) {
                int c = bc + j;
                v[j] = (c < 300) ? (at[a * 300 + c] + wt[w * 300 + c]) : 0.f;
            }
        }
#pragma unroll
        for (int j = 0; j < 8; ++j) out[j] = f2bf_rn(v[j]);
    }
    *(bf16x8*)&h[(size_t)i * PADD + bc] = out;
}

// ---------------- W pack: Wp[(kt*2+hl)*320 + n][k] (k=0..31 within kt), hi/lo ----------------
__global__ __launch_bounds__(256) void k_packW(const float* __restrict__ W,
                                               short* __restrict__ Wp) {
    int t = blockIdx.x * 256 + threadIdx.x;
    if (t >= 25600) return;
    int k8 = t & 3;
    int n = (t >> 2) % 320;
    int khl = (t >> 2) / 320;
    int kt = khl >> 1, hl = khl & 1;
    bf16x8 out;
#pragma unroll
    for (int j = 0; j < 8; ++j) {
        int gk = kt * 32 + k8 * 8 + j;
        float v = (gk < 300 && n < 300) ? W[gk * 300 + n] : 0.f;
        short hi = f2bf_rn(v);
        out[j] = hl ? f2bf_rn(v - bf2f(hi)) : hi;
    }
    *(bf16x8*)&Wp[(size_t)t * 8] = out;
}

// ---------------- GEMM: Cb[M,320](bf16) = A[M,320](bf16) * W, 16x16x32 MFMA, hi/lo ----------------
#define G_BM 128

__global__ __launch_bounds__(256, 2) void k_gemm4(const short* __restrict__ A,
                                                  const short* __restrict__ Wp,
                                                  short* __restrict__ Cb, int M) {
    __shared__ short As[128 * 32];        // [row][k], k-contiguous, 8 KB
    __shared__ short Bs[2 * 160 * 32];    // [hl][n][k], k-contiguous, 20 KB
    const int tid = threadIdx.x;
    const int wave = tid >> 6;
    const int lane = tid & 63;
    const int r15 = lane & 15;
    const int q = lane >> 4;
    const int wm = wave >> 1;             // 0..1 (row half)
    const int wn = wave & 1;              // 0..1 (col half)
    const int bm0 = blockIdx.x * G_BM;
    const int bn = blockIdx.y;            // 0..1

    f32x4 acc[4][5];
#pragma unroll
    for (int mi = 0; mi < 4; ++mi)
#pragma unroll
        for (int nt = 0; nt < 5; ++nt) acc[mi][nt] = (f32x4){0.f, 0.f, 0.f, 0.f};

    for (int kt = 0; kt < 10; ++kt) {
        // ---- stage A[bm0..+128][kt*32..+32] -> As ----
#pragma unroll
        for (int rr = 0; rr < 2; ++rr) {
            int u = rr * 256 + tid;        // 0..511
            int row = u >> 2, k8 = u & 3;
            int grow = bm0 + row;
            bf16x8 v;
            if (grow < M) {
                v = *(const bf16x8*)&A[(size_t)grow * PADD + kt * 32 + k8 * 8];
            } else {
#pragma unroll
                for (int j = 0; j < 8; ++j) v[j] = 0;
            }
            *(bf16x8*)&As[row * 32 + k8 * 8] = v;
        }
        // ---- stage B (hi+lo, 160 cols of this bn) -> Bs ----
#pragma unroll
        for (int rr = 0; rr < 5; ++rr) {
            int u = rr * 256 + tid;        // 0..1279
            int hl = u / 640;
            int rem = u - hl * 640;        // n_loc*4 + k8
            bf16x8 v = *(const bf16x8*)&Wp[((size_t)(kt * 2 + hl) * 1280 + (size_t)bn * 640 + rem) * 8];
            *(bf16x8*)&Bs[hl * 5120 + rem * 8] = v;
        }
        __syncthreads();

        bf16x8 af[4];
#pragma unroll
        for (int mi = 0; mi < 4; ++mi)
            af[mi] = *(const bf16x8*)&As[(wm * 64 + mi * 16 + r15) * 32 + q * 8];
        bf16x8 bfh[5], bfl[5];
#pragma unroll
        for (int nt = 0; nt < 5; ++nt) {
            int nl = wn * 80 + nt * 16 + r15;
            bfh[nt] = *(const bf16x8*)&Bs[nl * 32 + q * 8];
            bfl[nt] = *(const bf16x8*)&Bs[5120 + nl * 32 + q * 8];
        }
#pragma unroll
        for (int nt = 0; nt < 5; ++nt) {
#pragma unroll
            for (int mi = 0; mi < 4; ++mi) {
                acc[mi][nt] = __builtin_amdgcn_mfma_f32_16x16x32_bf16(af[mi], bfh[nt], acc[mi][nt], 0, 0, 0);
                acc[mi][nt] = __builtin_amdgcn_mfma_f32_16x16x32_bf16(af[mi], bfl[nt], acc[mi][nt], 0, 0, 0);
            }
        }
        __syncthreads();
    }

#pragma unroll
    for (int mi = 0; mi < 4; ++mi) {
#pragma unroll
        for (int nt = 0; nt < 5; ++nt) {
            int col = bn * 160 + wn * 80 + nt * 16 + r15;
            int row0 = bm0 + wm * 64 + mi * 16 + q * 4;
            f32x4 c = acc[mi][nt];
#pragma unroll
            for (int reg = 0; reg < 4; ++reg) {
                int row = row0 + reg;
                if (row < M) Cb[(size_t)row * PADD + col] = f2bf_rn(c[reg]);
            }
        }
    }
}

// ---------------- aggregation: 32B chunks, x2 edge unroll (4 gathers in flight) ----------------
__global__ __launch_bounds__(256) void k_agg(const short* __restrict__ hw,
                                             const float* __restrict__ dinv,
                                             const unsigned* __restrict__ row_start,
                                             const uint2* __restrict__ edges,
                                             const float* __restrict__ b,
                                             short* __restrict__ hout, int n) {
    int idx = blockIdx.x * 256 + threadIdx.x;
    if (idx >= n * CH2) return;
    int i = idx / CH2;
    int c16 = idx - i * CH2;
    int bc = c16 * 16;
    short* outp = &hout[(size_t)i * PADD + bc];

    if (c16 == 19) {   // cols 304..319: all-pad (hw pad cols are exactly 0) -> output 0
        bf16x8 z;
#pragma unroll
        for (int j = 0; j < 8; ++j) z[j] = 0;
        *(bf16x8*)outp = z;
        *(bf16x8*)(outp + 8) = z;
        return;
    }

    float acc[16];
    if (c16 < 18) {
        const float4* pb = (const float4*)&b[bc];
        float4 b0 = pb[0], b1 = pb[1], b2 = pb[2], b3 = pb[3];
        acc[0] = b0.x;  acc[1] = b0.y;  acc[2] = b0.z;  acc[3] = b0.w;
        acc[4] = b1.x;  acc[5] = b1.y;  acc[6] = b1.z;  acc[7] = b1.w;
        acc[8] = b2.x;  acc[9] = b2.y;  acc[10] = b2.z; acc[11] = b2.w;
        acc[12] = b3.x; acc[13] = b3.y; acc[14] = b3.z; acc[15] = b3.w;
    } else {           // c16==18: cols 288..303, bias valid to 299
#pragma unroll
        for (int j = 0; j < 16; ++j) {
            int c = bc + j;
            acc[j] = (c < 300) ? b[c] : 0.f;
        }
    }

    float di = dinv[i];
    float sn = di * di;
    {
        const short* rs = &hw[(size_t)i * PADD + bc];
        bf16x8 s0 = *(const bf16x8*)rs;
        bf16x8 s1 = *(const bf16x8*)(rs + 8);
#pragma unroll
        for (int j = 0; j < 8; ++j) { acc[j] += sn * bf2f(s0[j]); acc[8 + j] += sn * bf2f(s1[j]); }
    }

    unsigned e0 = row_start[i], e1 = row_start[i + 1];
    unsigned e = e0;
    for (; e + 2 <= e1; e += 2) {
        uint2 p0 = edges[e], p1 = edges[e + 1];
        float v0 = u_as_f(p0.y), v1 = u_as_f(p1.y);
        const short* r0 = &hw[(size_t)p0.x * PADD + bc];
        const short* r1 = &hw[(size_t)p1.x * PADD + bc];
        bf16x8 a0 = *(const bf16x8*)r0;
        bf16x8 a1 = *(const bf16x8*)(r0 + 8);
        bf16x8 c0 = *(const bf16x8*)r1;
        bf16x8 c1 = *(const bf16x8*)(r1 + 8);
#pragma unroll
        for (int j = 0; j < 8; ++j) {
            acc[j]     += v0 * bf2f(a0[j]) + v1 * bf2f(c0[j]);
            acc[8 + j] += v0 * bf2f(a1[j]) + v1 * bf2f(c1[j]);
        }
    }
    if (e < e1) {
        uint2 p0 = edges[e];
        float v0 = u_as_f(p0.y);
        const short* r0 = &hw[(size_t)p0.x * PADD + bc];
        bf16x8 a0 = *(const bf16x8*)r0;
        bf16x8 a1 = *(const bf16x8*)(r0 + 8);
#pragma unroll
        for (int j = 0; j < 8; ++j) {
            acc[j]     += v0 * bf2f(a0[j]);
            acc[8 + j] += v0 * bf2f(a1[j]);
        }
    }

    bf16x8 o0, o1;
#pragma unroll
    for (int j = 0; j < 8; ++j) { o0[j] = f2bf_rn(acc[j]); o1[j] = f2bf_rn(acc[8 + j]); }
    *(bf16x8*)outp = o0;
    *(bf16x8*)(outp + 8) = o1;
}

// ---------------- graph boundaries (batch sorted) ----------------
__global__ __launch_bounds__(128) void k_gstart(const int* __restrict__ batch,
                                                int* __restrict__ gstart, int n, int ngraph) {
    int g = threadIdx.x;
    if (g > ngraph) return;
    if (g == ngraph) { gstart[g] = n; return; }
    int lo = 0, hi = n;
    while (lo < hi) {
        int mid = (lo + hi) >> 1;
        if (batch[mid] < g) lo = mid + 1; else hi = mid;
    }
    gstart[g] = lo;
}

// ---------------- pool: 64 graphs x 16 chunks, vectorized row-major reads ----------------
__global__ __launch_bounds__(256) void k_pool(const short* __restrict__ h,
                                              const int* __restrict__ gstart,
                                              float* __restrict__ psum) {
    __shared__ float red[6][40][8];
    int g = blockIdx.x >> 4;
    int chunk = blockIdx.x & 15;
    int lo = gstart[g], hi = gstart[g + 1];
    int cnt = hi - lo;
    int s = lo + (int)((long)cnt * chunk / 16);
    int e2 = lo + (int)((long)cnt * (chunk + 1) / 16);
    int t = threadIdx.x;
    int c8 = t % 40;
    int rl = t / 40;                 // 0..6 (rl==6 lanes inactive)
    bool live = (rl < 6) && (c8 < 38);

    float acc[8];
#pragma unroll
    for (int j = 0; j < 8; ++j) acc[j] = 0.f;

    if (live) {
        int r = s + rl;
        for (; r + 6 < e2; r += 12) {
            bf16x8 v0 = *(const bf16x8*)&h[(size_t)r * PADD + c8 * 8];
            bf16x8 v1 = *(const bf16x8*)&h[(size_t)(r + 6) * PADD + c8 * 8];
#pragma unroll
            for (int j = 0; j < 8; ++j) acc[j] += bf2f(v0[j]) + bf2f(v1[j]);
        }
        if (r < e2) {
            bf16x8 v0 = *(const bf16x8*)&h[(size_t)r * PADD + c8 * 8];
#pragma unroll
            for (int j = 0; j < 8; ++j) acc[j] += bf2f(v0[j]);
        }
    }
    if (rl < 6) {
#pragma unroll
        for (int j = 0; j < 8; ++j) red[rl][c8][j] = acc[j];
    }
    __syncthreads();
    if (t < 38) {
        float s8[8];
#pragma unroll
        for (int j = 0; j < 8; ++j)
            s8[j] = red[0][t][j] + red[1][t][j] + red[2][t][j] +
                    red[3][t][j] + red[4][t][j] + red[5][t][j];
#pragma unroll
        for (int j = 0; j < 8; ++j) {
            int c = t * 8 + j;
            if (c < 300) atomicAdd(&psum[g * 300 + c], s8[j]);
        }
    }
}

__global__ __launch_bounds__(256) void k_div(const float* __restrict__ psum,
                                             const int* __restrict__ gstart,
                                             float* __restrict__ out) {
    int j = blockIdx.x * 256 + threadIdx.x;
    if (j >= NGRAPH_C * 300) return;
    int g = j / 300;
    int c2 = gstart[g + 1] - gstart[g];
    out[j] = psum[j] / (float)(c2 > 0 ? c2 : 1);
}

// ---------------- launch ----------------
extern "C" void kernel_launch(void* const* d_in, const int* in_sizes, int n_in,
                              void* d_out, int out_size, void* d_ws, size_t ws_size,
                              hipStream_t stream) {
    const int*   x     = (const int*)d_in[0];
    const int*   ei    = (const int*)d_in[1];
    const int*   batch = (const int*)d_in[2];
    const float* at    = (const float*)d_in[3];
    const float* wt    = (const float*)d_in[4];
    const float* W     = (const float*)d_in[5];
    const float* b     = (const float*)d_in[6];

    const int n = in_sizes[0] / 2;   // 100000
    const int e = in_sizes[1] / 2;   // 800000

    char* ws = (char*)d_ws;
    size_t off = 0;
    auto carve = [&](size_t bytes) {
        void* p = ws + off;
        off += (bytes + 255) & ~(size_t)255;
        return p;
    };
    short*    h         = (short*)carve((size_t)n * PADD * 2);
    short*    hw        = (short*)carve((size_t)n * PADD * 2);
    float*    dinv      = (float*)carve((size_t)n * 4);
    unsigned* counts    = (unsigned*)carve((size_t)n * 4);
    unsigned* fill      = (unsigned*)carve((size_t)n * 4);
    unsigned* row_start = (unsigned*)carve((size_t)(n + 1) * 4);
    unsigned* partials  = (unsigned*)carve(1024 * 4);
    uint2*    edges     = (uint2*)carve((size_t)e * 8);
    int*      gstart    = (int*)carve(65 * 4);
    float*    psum      = (float*)carve((size_t)NGRAPH_C * 300 * 4);
    short*    Wp        = (short*)carve((size_t)25600 * 8 * 2);

    const int* src = ei;
    const int* dst = ei + e;

    hipMemsetAsync(counts, 0, (size_t)n * 4, stream);
    hipMemsetAsync(fill, 0, (size_t)n * 4, stream);
    hipMemsetAsync(psum, 0, (size_t)NGRAPH_C * 300 * 4, stream);

    int eb = (e + 255) / 256;
    int nb256 = (n + 255) / 256;
    int NB = (n + 1023) / 1024;  // 98

    k_count<<<eb, 256, 0, stream>>>(dst, counts, e);
    k_dinv<<<nb256, 256, 0, stream>>>(counts, dinv, n);
    k_blocksum<<<NB, 256, 0, stream>>>(counts, partials, n);
    k_scanpartials<<<1, 128, 0, stream>>>(partials, NB);
    k_scanblock<<<NB, 256, 0, stream>>>(counts, partials, row_start, n);
    k_fill<<<eb, 256, 0, stream>>>(src, dst, row_start, fill, edges, dinv, e);
    k_gstart<<<1, 128, 0, stream>>>(batch, gstart, n, NGRAPH_C);
    k_packW<<<(25600 + 255) / 256, 256, 0, stream>>>(W, Wp);

    int gb = (n * CH + 255) / 256;
    k_embed<<<gb, 256, 0, stream>>>(x, at, wt, h, n);

    int gb2 = (n * CH2 + 255) / 256;
    dim3 ggrid((n + G_BM - 1) / G_BM, 2);
    for (int hop = 0; hop < 3; ++hop) {
        k_gemm4<<<ggrid, 256, 0, stream>>>(h, Wp, hw, n);
        k_agg<<<gb2, 256, 0, stream>>>(hw, dinv, row_start, edges, b, h, n);
    }

    k_pool<<<NGRAPH_C * 16, 256, 0, stream>>>(h, gstart, psum);
    k_div<<<(NGRAPH_C * 300 + 255) / 256, 256, 0, stream>>>(psum, gstart, (float*)d_out);
}

// Round 8
// 543.580 us; speedup vs baseline: 5.6727x; 1.1724x over previous
//
#include <hip/hip_runtime.h>
#include <hip/hip_bf16.h>

#define N_NODES_C 100000
#define N_EDGES_C 800000
#define DIM_C 300
#define PADD 320          // padded feature dim
#define CH 40             // 16B bf16x8 chunks per row (320/8)
#define CH2 20            // 32B chunks per row
#define NGRAPH_C 64

typedef short bf16x8 __attribute__((ext_vector_type(8)));
typedef float f32x4 __attribute__((ext_vector_type(4)));

// ---- bf16 helpers (manual RN-even) ----
__device__ __forceinline__ unsigned f_as_u(float f) { union { float f; unsigned u; } c; c.f = f; return c.u; }
__device__ __forceinline__ float u_as_f(unsigned u) { union { unsigned u; float f; } c; c.u = u; return c.f; }
__device__ __forceinline__ short f2bf_rn(float f) {
    unsigned u = f_as_u(f);
    unsigned r = (u + 0x7FFFu + ((u >> 16) & 1u)) >> 16;
    return (short)r;
}
__device__ __forceinline__ float bf2f(short s) { return u_as_f(((unsigned)(unsigned short)s) << 16); }

// ---------------- degree count ----------------
__global__ __launch_bounds__(256) void k_count(const int* __restrict__ dst,
                                               unsigned* __restrict__ counts, int e) {
    int i = blockIdx.x * 256 + threadIdx.x;
    if (i < e) atomicAdd(&counts[dst[i]], 1u);
}

__global__ __launch_bounds__(256) void k_dinv(const unsigned* __restrict__ counts,
                                              float* __restrict__ dinv, int n) {
    int i = blockIdx.x * 256 + threadIdx.x;
    if (i < n) dinv[i] = rsqrtf((float)(counts[i] + 1u));  // +1 self loop
}

// ---------------- 2-level exclusive scan over counts ----------------
__global__ __launch_bounds__(256) void k_blocksum(const unsigned* __restrict__ counts,
                                                  unsigned* __restrict__ partials, int n) {
    __shared__ unsigned s[256];
    int base = blockIdx.x * 1024;
    unsigned sum = 0;
    for (int j = threadIdx.x; j < 1024; j += 256) {
        int i = base + j;
        sum += (i < n) ? counts[i] : 0u;
    }
    s[threadIdx.x] = sum;
    __syncthreads();
    for (int off = 128; off > 0; off >>= 1) {
        if (threadIdx.x < (unsigned)off) s[threadIdx.x] += s[threadIdx.x + off];
        __syncthreads();
    }
    if (threadIdx.x == 0) partials[blockIdx.x] = s[0];
}

__global__ __launch_bounds__(128) void k_scanpartials(unsigned* __restrict__ partials, int nb) {
    __shared__ unsigned s[128];
    int t = threadIdx.x;
    s[t] = (t < nb) ? partials[t] : 0u;
    __syncthreads();
    if (t == 0) {
        unsigned run = 0;
        for (int i = 0; i < nb; ++i) { unsigned v = s[i]; s[i] = run; run += v; }
    }
    __syncthreads();
    if (t < nb) partials[t] = s[t];
}

__global__ __launch_bounds__(256) void k_scanblock(const unsigned* __restrict__ counts,
                                                   const unsigned* __restrict__ partials,
                                                   unsigned* __restrict__ row_start, int n) {
    __shared__ unsigned s[256];
    int base = blockIdx.x * 1024;
    int t = threadIdx.x;
    unsigned v[4];
    unsigned tsum = 0;
#pragma unroll
    for (int j = 0; j < 4; ++j) {
        int i = base + t * 4 + j;
        v[j] = (i < n) ? counts[i] : 0u;
        tsum += v[j];
    }
    s[t] = tsum;
    __syncthreads();
    for (int off = 1; off < 256; off <<= 1) {
        unsigned x = (t >= off) ? s[t - off] : 0u;
        __syncthreads();
        s[t] += x;
        __syncthreads();
    }
    unsigned excl = (t > 0 ? s[t - 1] : 0u) + partials[blockIdx.x];
#pragma unroll
    for (int j = 0; j < 4; ++j) {
        int i = base + t * 4 + j;
        if (i < n) {
            row_start[i] = excl;
            excl += v[j];
            if (i == n - 1) row_start[n] = excl;
        }
    }
}

// ---------------- CSR fill: combined (col, val) uint2 ----------------
__global__ __launch_bounds__(256) void k_fill(const int* __restrict__ src, const int* __restrict__ dst,
                                              const unsigned* __restrict__ row_start,
                                              unsigned* __restrict__ fill,
                                              uint2* __restrict__ edges,
                                              const float* __restrict__ dinv, int e) {
    int i = blockIdx.x * 256 + threadIdx.x;
    if (i >= e) return;
    int d = dst[i], s0 = src[i];
    unsigned pos = row_start[d] + atomicAdd(&fill[d], 1u);
    uint2 p;
    p.x = (unsigned)s0;
    p.y = f_as_u(dinv[s0] * dinv[d]);
    edges[pos] = p;
}

// ---------------- scalar propagation: u_out = A_norm * u_in (u_in==NULL -> ones) ----------------
__global__ __launch_bounds__(256) void k_prop1(const float* __restrict__ u_in,
                                               const unsigned* __restrict__ row_start,
                                               const uint2* __restrict__ edges,
                                               const float* __restrict__ dinv,
                                               float* __restrict__ u_out, int n) {
    int i = blockIdx.x * 256 + threadIdx.x;
    if (i >= n) return;
    float di = dinv[i];
    float acc = di * di * (u_in ? u_in[i] : 1.0f);
    unsigned e0 = row_start[i], e1 = row_start[i + 1];
    for (unsigned e = e0; e < e1; ++e) {
        uint2 p = edges[e];
        float uv = u_in ? u_in[p.x] : 1.0f;
        acc += u_as_f(p.y) * uv;
    }
    u_out[i] = acc;
}

// ---------------- per-graph sums of u1,u2 ----------------
__global__ __launch_bounds__(256) void k_su(const float* __restrict__ u1,
                                            const float* __restrict__ u2,
                                            const int* __restrict__ gstart,
                                            float* __restrict__ su1, float* __restrict__ su2) {
    __shared__ float r1[256], r2[256];
    int g = blockIdx.x;
    int lo = gstart[g], hi = gstart[g + 1];
    int t = threadIdx.x;
    float s1 = 0.f, s2 = 0.f;
    for (int i = lo + t; i < hi; i += 256) { s1 += u1[i]; s2 += u2[i]; }
    r1[t] = s1; r2[t] = s2;
    __syncthreads();
    for (int off = 128; off > 0; off >>= 1) {
        if (t < off) { r1[t] += r1[t + off]; r2[t] += r2[t + off]; }
        __syncthreads();
    }
    if (t == 0) { su1[g] = r1[0]; su2[g] = r2[0]; }
}

// ---------------- small fp32 GEMM 300x300: C = A * B ----------------
__global__ __launch_bounds__(256) void k_mm(const float* __restrict__ A,
                                            const float* __restrict__ B,
                                            float* __restrict__ C) {
    int j = blockIdx.x * 256 + threadIdx.x;
    if (j >= 300 * 300) return;
    int r = j / 300, c = j - r * 300;
    float s = 0.f;
    for (int k = 0; k < 300; ++k) s += A[r * 300 + k] * B[k * 300 + c];
    C[j] = s;
}

// ---------------- embedding -> bf16 padded rows ----------------
__global__ __launch_bounds__(256) void k_embed(const int* __restrict__ x,
                                               const float* __restrict__ at,
                                               const float* __restrict__ wt,
                                               short* __restrict__ h, int n) {
    int idx = blockIdx.x * 256 + threadIdx.x;
    if (idx >= n * CH) return;
    int i = idx / CH;
    int c8 = idx - i * CH;
    int bc = c8 * 8;
    bf16x8 out;
    if (c8 >= 38) {
#pragma unroll
        for (int j = 0; j < 8; ++j) out[j] = 0;
    } else {
        int a = x[2 * i], w = x[2 * i + 1];
        float v[8];
        if (c8 < 37) {
            const float4* pa = (const float4*)&at[a * 300 + bc];
            const float4* pw = (const float4*)&wt[w * 300 + bc];
            float4 a0 = pa[0], a1 = pa[1], w0 = pw[0], w1 = pw[1];
            v[0] = a0.x + w0.x; v[1] = a0.y + w0.y; v[2] = a0.z + w0.z; v[3] = a0.w + w0.w;
            v[4] = a1.x + w1.x; v[5] = a1.y + w1.y; v[6] = a1.z + w1.z; v[7] = a1.w + w1.w;
        } else {
#pragma unroll
            for (int j = 0; j < 8; ++j) {
                int c = bc + j;
                v[j] = (c < 300) ? (at[a * 300 + c] + wt[w * 300 + c]) : 0.f;
            }
        }
#pragma unroll
        for (int j = 0; j < 8; ++j) out[j] = f2bf_rn(v[j]);
    }
    *(bf16x8*)&h[(size_t)i * PADD + bc] = out;
}

// ---------------- feature propagation: z_out = bf16( A_norm z_in ), 32B chunks ----------------
__global__ __launch_bounds__(256) void k_prop(const short* __restrict__ zin,
                                              const float* __restrict__ dinv,
                                              const unsigned* __restrict__ row_start,
                                              const uint2* __restrict__ edges,
                                              short* __restrict__ zout, int n) {
    int idx = blockIdx.x * 256 + threadIdx.x;
    if (idx >= n * CH2) return;
    int i = idx / CH2;
    int c16 = idx - i * CH2;
    int bc = c16 * 16;
    short* outp = &zout[(size_t)i * PADD + bc];

    if (c16 == 19) {   // cols 304..319: all-pad, stays zero
        bf16x8 z;
#pragma unroll
        for (int j = 0; j < 8; ++j) z[j] = 0;
        *(bf16x8*)outp = z;
        *(bf16x8*)(outp + 8) = z;
        return;
    }

    float acc[16];
#pragma unroll
    for (int j = 0; j < 16; ++j) acc[j] = 0.f;

    float di = dinv[i];
    float sn = di * di;
    {
        const short* rs = &zin[(size_t)i * PADD + bc];
        bf16x8 s0 = *(const bf16x8*)rs;
        bf16x8 s1 = *(const bf16x8*)(rs + 8);
#pragma unroll
        for (int j = 0; j < 8; ++j) { acc[j] += sn * bf2f(s0[j]); acc[8 + j] += sn * bf2f(s1[j]); }
    }

    unsigned e0 = row_start[i], e1 = row_start[i + 1];
    unsigned e = e0;
    for (; e + 2 <= e1; e += 2) {
        uint2 p0 = edges[e], p1 = edges[e + 1];
        float v0 = u_as_f(p0.y), v1 = u_as_f(p1.y);
        const short* r0 = &zin[(size_t)p0.x * PADD + bc];
        const short* r1 = &zin[(size_t)p1.x * PADD + bc];
        bf16x8 a0 = *(const bf16x8*)r0;
        bf16x8 a1 = *(const bf16x8*)(r0 + 8);
        bf16x8 c0 = *(const bf16x8*)r1;
        bf16x8 c1 = *(const bf16x8*)(r1 + 8);
#pragma unroll
        for (int j = 0; j < 8; ++j) {
            acc[j]     += v0 * bf2f(a0[j]) + v1 * bf2f(c0[j]);
            acc[8 + j] += v0 * bf2f(a1[j]) + v1 * bf2f(c1[j]);
        }
    }
    if (e < e1) {
        uint2 p0 = edges[e];
        float v0 = u_as_f(p0.y);
        const short* r0 = &zin[(size_t)p0.x * PADD + bc];
        bf16x8 a0 = *(const bf16x8*)r0;
        bf16x8 a1 = *(const bf16x8*)(r0 + 8);
#pragma unroll
        for (int j = 0; j < 8; ++j) {
            acc[j]     += v0 * bf2f(a0[j]);
            acc[8 + j] += v0 * bf2f(a1[j]);
        }
    }

    bf16x8 o0, o1;
#pragma unroll
    for (int j = 0; j < 8; ++j) { o0[j] = f2bf_rn(acc[j]); o1[j] = f2bf_rn(acc[8 + j]); }
    *(bf16x8*)outp = o0;
    *(bf16x8*)(outp + 8) = o1;
}

// ---------------- graph boundaries (batch sorted) ----------------
__global__ __launch_bounds__(128) void k_gstart(const int* __restrict__ batch,
                                                int* __restrict__ gstart, int n, int ngraph) {
    int g = threadIdx.x;
    if (g > ngraph) return;
    if (g == ngraph) { gstart[g] = n; return; }
    int lo = 0, hi = n;
    while (lo < hi) {
        int mid = (lo + hi) >> 1;
        if (batch[mid] < g) lo = mid + 1; else hi = mid;
    }
    gstart[g] = lo;
}

// ---------------- pool: 64 graphs x 16 chunks, vectorized row-major reads ----------------
__global__ __launch_bounds__(256) void k_pool(const short* __restrict__ h,
                                              const int* __restrict__ gstart,
                                              float* __restrict__ psum) {
    __shared__ float red[6][40][8];
    int g = blockIdx.x >> 4;
    int chunk = blockIdx.x & 15;
    int lo = gstart[g], hi = gstart[g + 1];
    int cnt = hi - lo;
    int s = lo + (int)((long)cnt * chunk / 16);
    int e2 = lo + (int)((long)cnt * (chunk + 1) / 16);
    int t = threadIdx.x;
    int c8 = t % 40;
    int rl = t / 40;                 // 0..6 (rl==6 lanes inactive)
    bool live = (rl < 6) && (c8 < 38);

    float acc[8];
#pragma unroll
    for (int j = 0; j < 8; ++j) acc[j] = 0.f;

    if (live) {
        int r = s + rl;
        for (; r + 6 < e2; r += 12) {
            bf16x8 v0 = *(const bf16x8*)&h[(size_t)r * PADD + c8 * 8];
            bf16x8 v1 = *(const bf16x8*)&h[(size_t)(r + 6) * PADD + c8 * 8];
#pragma unroll
            for (int j = 0; j < 8; ++j) acc[j] += bf2f(v0[j]) + bf2f(v1[j]);
        }
        if (r < e2) {
            bf16x8 v0 = *(const bf16x8*)&h[(size_t)r * PADD + c8 * 8];
#pragma unroll
            for (int j = 0; j < 8; ++j) acc[j] += bf2f(v0[j]);
        }
    }
    if (rl < 6) {
#pragma unroll
        for (int j = 0; j < 8; ++j) red[rl][c8][j] = acc[j];
    }
    __syncthreads();
    if (t < 38) {
        float s8[8];
#pragma unroll
        for (int j = 0; j < 8; ++j)
            s8[j] = red[0][t][j] + red[1][t][j] + red[2][t][j] +
                    red[3][t][j] + red[4][t][j] + red[5][t][j];
#pragma unroll
        for (int j = 0; j < 8; ++j) {
            int c = t * 8 + j;
            if (c < 300) atomicAdd(&psum[g * 300 + c], s8[j]);
        }
    }
}

// ---------------- final: out = (psum*W3 + su2*(b^T W2) + su1*(b^T W) + cnt*b) / max(cnt,1) ----------------
__global__ __launch_bounds__(256) void k_out(const float* __restrict__ psum,
                                             const float* __restrict__ su1,
                                             const float* __restrict__ su2,
                                             const int* __restrict__ gstart,
                                             const float* __restrict__ W,
                                             const float* __restrict__ W2,
                                             const float* __restrict__ W3,
                                             const float* __restrict__ b,
                                             float* __restrict__ out) {
    int j = blockIdx.x * 256 + threadIdx.x;
    if (j >= NGRAPH_C * 300) return;
    int g = j / 300, c = j - g * 300;
    float s = 0.f, bw1 = 0.f, bw2 = 0.f;
    for (int k = 0; k < 300; ++k) {
        s   += psum[g * 300 + k] * W3[k * 300 + c];
        bw1 += b[k] * W[k * 300 + c];
        bw2 += b[k] * W2[k * 300 + c];
    }
    int cnt = gstart[g + 1] - gstart[g];
    float tot = s + su2[g] * bw2 + su1[g] * bw1 + (float)cnt * b[c];
    out[j] = tot / (float)(cnt > 0 ? cnt : 1);
}

// ---------------- launch ----------------
extern "C" void kernel_launch(void* const* d_in, const int* in_sizes, int n_in,
                              void* d_out, int out_size, void* d_ws, size_t ws_size,
                              hipStream_t stream) {
    const int*   x     = (const int*)d_in[0];
    const int*   ei    = (const int*)d_in[1];
    const int*   batch = (const int*)d_in[2];
    const float* at    = (const float*)d_in[3];
    const float* wt    = (const float*)d_in[4];
    const float* W     = (const float*)d_in[5];
    const float* b     = (const float*)d_in[6];

    const int n = in_sizes[0] / 2;   // 100000
    const int e = in_sizes[1] / 2;   // 800000

    char* ws = (char*)d_ws;
    size_t off = 0;
    auto carve = [&](size_t bytes) {
        void* p = ws + off;
        off += (bytes + 255) & ~(size_t)255;
        return p;
    };
    short*    zA        = (short*)carve((size_t)n * PADD * 2);
    short*    zB        = (short*)carve((size_t)n * PADD * 2);
    float*    dinv      = (float*)carve((size_t)n * 4);
    unsigned* counts    = (unsigned*)carve((size_t)n * 4);
    unsigned* fill      = (unsigned*)carve((size_t)n * 4);
    unsigned* row_start = (unsigned*)carve((size_t)(n + 1) * 4);
    unsigned* partials  = (unsigned*)carve(1024 * 4);
    uint2*    edges     = (uint2*)carve((size_t)e * 8);
    int*      gstart    = (int*)carve(65 * 4);
    float*    psum      = (float*)carve((size_t)NGRAPH_C * 300 * 4);
    float*    u1        = (float*)carve((size_t)n * 4);
    float*    u2        = (float*)carve((size_t)n * 4);
    float*    su1       = (float*)carve(64 * 4);
    float*    su2       = (float*)carve(64 * 4);
    float*    W2        = (float*)carve((size_t)300 * 300 * 4);
    float*    W3        = (float*)carve((size_t)300 * 300 * 4);

    const int* src = ei;
    const int* dst = ei + e;

    hipMemsetAsync(counts, 0, (size_t)n * 4, stream);
    hipMemsetAsync(fill, 0, (size_t)n * 4, stream);
    hipMemsetAsync(psum, 0, (size_t)NGRAPH_C * 300 * 4, stream);

    int eb = (e + 255) / 256;
    int nb256 = (n + 255) / 256;
    int NB = (n + 1023) / 1024;  // 98

    k_count<<<eb, 256, 0, stream>>>(dst, counts, e);
    k_dinv<<<nb256, 256, 0, stream>>>(counts, dinv, n);
    k_blocksum<<<NB, 256, 0, stream>>>(counts, partials, n);
    k_scanpartials<<<1, 128, 0, stream>>>(partials, NB);
    k_scanblock<<<NB, 256, 0, stream>>>(counts, partials, row_start, n);
    k_fill<<<eb, 256, 0, stream>>>(src, dst, row_start, fill, edges, dinv, e);
    k_gstart<<<1, 128, 0, stream>>>(batch, gstart, n, NGRAPH_C);

    // scalar propagations: u1 = A*1, u2 = A*u1; per-graph sums
    k_prop1<<<nb256, 256, 0, stream>>>((const float*)nullptr, row_start, edges, dinv, u1, n);
    k_prop1<<<nb256, 256, 0, stream>>>(u1, row_start, edges, dinv, u2, n);
    k_su<<<NGRAPH_C, 256, 0, stream>>>(u1, u2, gstart, su1, su2);

    // W powers (exact fp32)
    k_mm<<<(300 * 300 + 255) / 256, 256, 0, stream>>>(W, W, W2);
    k_mm<<<(300 * 300 + 255) / 256, 256, 0, stream>>>(W2, W, W3);

    // z0 = embed; z3 = A^3 z0 (bf16 propagation, ping-pong)
    int gb = (n * CH + 255) / 256;
    k_embed<<<gb, 256, 0, stream>>>(x, at, wt, zA, n);
    int gb2 = (n * CH2 + 255) / 256;
    k_prop<<<gb2, 256, 0, stream>>>(zA, dinv, row_start, edges, zB, n);
    k_prop<<<gb2, 256, 0, stream>>>(zB, dinv, row_start, edges, zA, n);
    k_prop<<<gb2, 256, 0, stream>>>(zA, dinv, row_start, edges, zB, n);

    k_pool<<<NGRAPH_C * 16, 256, 0, stream>>>(zB, gstart, psum);
    k_out<<<(NGRAPH_C * 300 + 255) / 256, 256, 0, stream>>>(psum, su1, su2, gstart,
                                                            W, W2, W3, b, (float*)d_out);
}